// Round 4
// baseline (1520.865 us; speedup 1.0000x reference)
//
#include <hip/hip_runtime.h>

#define NN 100000
#define NE 1200000
#define NG 2048

static inline int cdiv(long long a, int b) { return (int)((a + b - 1) / b); }

// ---------------- CSR build: histogram / dinv / scan / scatter ----------------
__global__ void k_hist(const int* __restrict__ col, int* __restrict__ cnt, int E) {
    int e = blockIdx.x * blockDim.x + threadIdx.x;
    if (e < E) atomicAdd(&cnt[col[e]], 1);
}

__global__ void k_dinv(const int* __restrict__ cnt, float* __restrict__ dinv, int N) {
    int n = blockIdx.x * blockDim.x + threadIdx.x;
    if (n < N) {
        int c = cnt[n];
        dinv[n] = c > 0 ? rsqrtf((float)c) : 0.f;
    }
}

__global__ void k_scan1(const int* __restrict__ cnt, int* __restrict__ excl,
                        int* __restrict__ btot, int N) {
    __shared__ int s[256];
    int tid = threadIdx.x;
    int i = blockIdx.x * 256 + tid;
    int v = (i < N) ? cnt[i] : 0;
    s[tid] = v;
    __syncthreads();
    for (int off = 1; off < 256; off <<= 1) {
        int t = (tid >= off) ? s[tid - off] : 0;
        __syncthreads();
        s[tid] += t;
        __syncthreads();
    }
    if (i < N) excl[i] = s[tid] - v;
    if (tid == 255) btot[blockIdx.x] = s[255];
}

__global__ void k_scan2(const int* __restrict__ btot, int* __restrict__ boff, int NB) {
    __shared__ int s[512];
    int tid = threadIdx.x;
    int v = (tid < NB) ? btot[tid] : 0;
    s[tid] = v;
    __syncthreads();
    for (int off = 1; off < 512; off <<= 1) {
        int t = (tid >= off) ? s[tid - off] : 0;
        __syncthreads();
        s[tid] += t;
        __syncthreads();
    }
    if (tid < NB) boff[tid] = s[tid] - v;
}

__global__ void k_scan3(const int* __restrict__ excl, const int* __restrict__ boff,
                        int* __restrict__ rowptr, int* __restrict__ cursor, int N) {
    int i = blockIdx.x * blockDim.x + threadIdx.x;
    if (i < N) {
        int rp = excl[i] + boff[i >> 8];
        rowptr[i] = rp;
        cursor[i] = rp;
    }
    if (i == 0) rowptr[N] = NE;
}

__global__ void k_scatter(const int* __restrict__ row, const int* __restrict__ col,
                          int* __restrict__ cursor, int* __restrict__ esrc, int E) {
    int e = blockIdx.x * blockDim.x + threadIdx.x;
    if (e < E) {
        int c = col[e];
        int p = atomicAdd(&cursor[c], 1);
        esrc[p] = row[e];
    }
}

// s[n] = dinv[n] * sum_in dinv[r]   (= A_norm applied to the all-ones vector)
__global__ void k_s(const int* __restrict__ rowptr, const int* __restrict__ esrc,
                    const float* __restrict__ dinv, float* __restrict__ s, int N) {
    int n = blockIdx.x * blockDim.x + threadIdx.x;
    if (n >= N) return;
    int beg = rowptr[n], end = rowptr[n + 1];
    float a = 0.f;
    int p = beg;
    for (; p + 3 < end; p += 4) {
        int r0 = esrc[p], r1 = esrc[p + 1], r2 = esrc[p + 2], r3 = esrc[p + 3];
        a += (dinv[r0] + dinv[r1]) + (dinv[r2] + dinv[r3]);
    }
    for (; p < end; ++p) a += dinv[esrc[p]];
    s[n] = a * dinv[n];
}

// ---------------- layer-1 input transforms: A = (x@w1i)*dinv, R = x@w1r + b ----------------
__global__ void k_mm1(const float* __restrict__ x,
                      const float* __restrict__ w1i, const float* __restrict__ w1r,
                      const float* __restrict__ b1, const float* __restrict__ dinv,
                      float4* __restrict__ A4, float4* __restrict__ R4, int N) {
    __shared__ float4 Wi[900];  // [3][75][4] float4  (w1i)
    __shared__ float4 Wr[900];  // (w1r)
    __shared__ float4 Bs[12];
    const float4* wi4 = (const float4*)w1i;
    const float4* wr4 = (const float4*)w1r;
    for (int i = threadIdx.x; i < 900; i += blockDim.x) { Wi[i] = wi4[i]; Wr[i] = wr4[i]; }
    if (threadIdx.x < 12) Bs[threadIdx.x] = ((const float4*)b1)[threadIdx.x];
    __syncthreads();
    const int total = N * 24;
    const int stride = gridDim.x * blockDim.x;
    for (int idx = blockIdx.x * blockDim.x + threadIdx.x; idx < total; idx += stride) {
        int n = idx / 24;
        int q = idx - n * 24;
        int isA = q < 12;
        int q2 = isA ? q : q - 12;
        int k = q2 >> 2, o4 = q2 & 3;
        const float* xp = x + (size_t)n * 75;
        const float4* wp = (isA ? Wi : Wr) + (k * 75) * 4 + o4;
        float4 acc = isA ? make_float4(0.f, 0.f, 0.f, 0.f) : Bs[q2];
#pragma unroll
        for (int f = 0; f < 75; ++f) {
            float xv = xp[f];
            float4 w = wp[f * 4];
            acc.x = fmaf(xv, w.x, acc.x);
            acc.y = fmaf(xv, w.y, acc.y);
            acc.z = fmaf(xv, w.z, acc.z);
            acc.w = fmaf(xv, w.w, acc.w);
        }
        if (isA) {
            float dn = dinv[n];
            acc.x *= dn; acc.y *= dn; acc.z *= dn; acc.w *= dn;
            A4[(size_t)n * 12 + q2] = acc;
        } else {
            R4[(size_t)n * 12 + q2] = acc;
        }
    }
}

// ---------------- CSR-gather prop, float4, optional root+relu epilogue ----------------
// v = dinv[n] * sum_in src[r, q];  if HAS_R: v = relu(v + R[n,q])
// WRITE_RAW -> raw4 = v ; WRITE_SCALED -> scaled4 = v * dinv[n]
template <int FC4, int HAS_R, int WRITE_RAW, int WRITE_SCALED>
__global__ void k_prop(const float4* __restrict__ src4, const float4* __restrict__ R4,
                       const int* __restrict__ rowptr, const int* __restrict__ esrc,
                       const float* __restrict__ dinv,
                       float4* __restrict__ raw4, float4* __restrict__ scaled4, int N) {
    const int total = N * FC4;
    const int stride = gridDim.x * blockDim.x;
    for (int idx = blockIdx.x * blockDim.x + threadIdx.x; idx < total; idx += stride) {
        int n = idx / FC4;
        int q = idx - n * FC4;
        int beg = rowptr[n], end = rowptr[n + 1];
        float ax = 0.f, ay = 0.f, az = 0.f, aw = 0.f;
        int p = beg;
        for (; p + 3 < end; p += 4) {
            int r0 = esrc[p], r1 = esrc[p + 1], r2 = esrc[p + 2], r3 = esrc[p + 3];
            float4 v0 = src4[(size_t)r0 * FC4 + q];
            float4 v1 = src4[(size_t)r1 * FC4 + q];
            float4 v2 = src4[(size_t)r2 * FC4 + q];
            float4 v3 = src4[(size_t)r3 * FC4 + q];
            ax += (v0.x + v1.x) + (v2.x + v3.x);
            ay += (v0.y + v1.y) + (v2.y + v3.y);
            az += (v0.z + v1.z) + (v2.z + v3.z);
            aw += (v0.w + v1.w) + (v2.w + v3.w);
        }
        for (; p < end; ++p) {
            int r = esrc[p];
            float4 v = src4[(size_t)r * FC4 + q];
            ax += v.x; ay += v.y; az += v.z; aw += v.w;
        }
        float dn = dinv[n];
        float4 v;
        v.x = ax * dn; v.y = ay * dn; v.z = az * dn; v.w = aw * dn;
        if (HAS_R) {
            float4 r = R4[idx];
            v.x = fmaxf(v.x + r.x, 0.f);
            v.y = fmaxf(v.y + r.y, 0.f);
            v.z = fmaxf(v.z + r.z, 0.f);
            v.w = fmaxf(v.w + r.w, 0.f);
        }
        if (WRITE_RAW) raw4[idx] = v;
        if (WRITE_SCALED) {
            float4 sv;
            sv.x = v.x * dn; sv.y = v.y * dn; sv.z = v.z * dn; sv.w = v.w * dn;
            scaled4[idx] = sv;
        }
    }
}

// ---------------- layer-1 t=1 epilogue: h1 = mean_k relu(agg2@w1w[k] + R) ----------------
__global__ void k_post1(const float4* __restrict__ A4, const float4* __restrict__ R4,
                        const float* __restrict__ w1w, const float* __restrict__ dinv,
                        float4* __restrict__ h14, float4* __restrict__ h1p4, int N) {
    __shared__ float4 Ws[192];  // [3][16][4] float4 of w1w[k][i][o]
    const float4* w4 = (const float4*)w1w;
    for (int i = threadIdx.x; i < 192; i += blockDim.x) Ws[i] = w4[i];
    __syncthreads();
    const int total = N * 4;
    const int stride = gridDim.x * blockDim.x;
    for (int idx = blockIdx.x * blockDim.x + threadIdx.x; idx < total; idx += stride) {
        int n = idx >> 2;
        int o4 = idx & 3;
        const float4* ap = A4 + (size_t)n * 12;
        float4 sum = make_float4(0.f, 0.f, 0.f, 0.f);
#pragma unroll
        for (int k = 0; k < 3; ++k) {
            float4 d = R4[(size_t)n * 12 + k * 4 + o4];
#pragma unroll
            for (int i4 = 0; i4 < 4; ++i4) {
                float4 av = ap[k * 4 + i4];
                float4 w0 = Ws[(k * 16 + i4 * 4 + 0) * 4 + o4];
                float4 w1 = Ws[(k * 16 + i4 * 4 + 1) * 4 + o4];
                float4 w2 = Ws[(k * 16 + i4 * 4 + 2) * 4 + o4];
                float4 w3 = Ws[(k * 16 + i4 * 4 + 3) * 4 + o4];
                d.x = fmaf(av.x, w0.x, fmaf(av.y, w1.x, fmaf(av.z, w2.x, fmaf(av.w, w3.x, d.x))));
                d.y = fmaf(av.x, w0.y, fmaf(av.y, w1.y, fmaf(av.z, w2.y, fmaf(av.w, w3.y, d.y))));
                d.z = fmaf(av.x, w0.z, fmaf(av.y, w1.z, fmaf(av.z, w2.z, fmaf(av.w, w3.z, d.z))));
                d.w = fmaf(av.x, w0.w, fmaf(av.y, w1.w, fmaf(av.z, w2.w, fmaf(av.w, w3.w, d.w))));
            }
            d.x = fmaxf(d.x, 0.f); d.y = fmaxf(d.y, 0.f);
            d.z = fmaxf(d.z, 0.f); d.w = fmaxf(d.w, 0.f);
            sum.x += d.x; sum.y += d.y; sum.z += d.z; sum.w += d.w;
        }
        const float third = 1.0f / 3.0f;
        sum.x *= third; sum.y *= third; sum.z *= third; sum.w *= third;
        h14[idx] = sum;
        float dn = dinv[n];
        float4 sp;
        sp.x = sum.x * dn; sp.y = sum.y * dn; sp.z = sum.z * dn; sp.w = sum.w * dn;
        h1p4[idx] = sp;
    }
}

// ---------------- precombine layer-2 + head weights into u-vectors ----------------
// u[0..15]=u0, u[16..31]=u1, u[32..47]=u2, u[48]=c0, u[49]=c1
__global__ void k_comb(const float* __restrict__ w2i, const float* __restrict__ w2w,
                       const float* __restrict__ w2r, const float* __restrict__ b2,
                       const float* __restrict__ wg, float* __restrict__ u) {
    __shared__ float t[3][64];
    int tid = threadIdx.x;  // 64 threads
#pragma unroll
    for (int k = 0; k < 3; ++k) {
        float a = 0.f;
        for (int j = 0; j < 64; ++j) a = fmaf(w2w[k * 4096 + tid * 64 + j], wg[j], a);
        t[k][tid] = a;
    }
    __syncthreads();
    const float third = 1.0f / 3.0f;
    if (tid < 16) {
        float a2 = 0.f, a1 = 0.f, a0 = 0.f;
        for (int k = 0; k < 3; ++k)
            for (int i = 0; i < 64; ++i) {
                float wi = w2i[k * 1024 + tid * 64 + i];
                float wr = w2r[k * 1024 + tid * 64 + i];
                a2 = fmaf(wi, t[k][i], a2);
                a1 = fmaf(wr, t[k][i], a1);
                a0 = fmaf(wr, wg[i], a0);
            }
        u[tid] = a0 * third;
        u[16 + tid] = a1 * third;
        u[32 + tid] = a2 * third;
    } else if (tid == 16) {
        float c0 = 0.f, c1 = 0.f;
        for (int k = 0; k < 3; ++k)
            for (int i = 0; i < 64; ++i) {
                float bv = b2[k * 64 + i];
                c0 = fmaf(bv, t[k][i], c0);
                c1 = fmaf(bv, wg[i], c1);
            }
        u[48] = c0 * third;
        u[49] = c1 * third;
    }
}

// ---------------- per-node score + pooled head ----------------
__global__ void k_initout(float* __restrict__ out, const float* __restrict__ bg, int G) {
    int g = blockIdx.x * blockDim.x + threadIdx.x;
    if (g < G) out[g] = bg[0];
}

__global__ void k_score(const float4* __restrict__ h14, const float4* __restrict__ g14,
                        const float4* __restrict__ g24, const float* __restrict__ s,
                        const float* __restrict__ u, const int* __restrict__ batch,
                        float* __restrict__ out, int N) {
    int idx = blockIdx.x * blockDim.x + threadIdx.x;
    if (idx >= N * 4) return;
    int n = idx >> 2;
    int j = idx & 3;
    float4 a = h14[idx], b = g14[idx], c = g24[idx];
    float4 u0 = ((const float4*)u)[j];
    float4 u1 = ((const float4*)u)[4 + j];
    float4 u2 = ((const float4*)u)[8 + j];
    float v = a.x * u0.x + a.y * u0.y + a.z * u0.z + a.w * u0.w
            + b.x * u1.x + b.y * u1.y + b.z * u1.z + b.w * u1.w
            + c.x * u2.x + c.y * u2.y + c.z * u2.z + c.w * u2.w;
    v += __shfl_down(v, 2, 4);
    v += __shfl_down(v, 1, 4);
    if (j == 0) {
        v += s[n] * u[48] + u[49];
        atomicAdd(&out[batch[n]], v);
    }
}

extern "C" void kernel_launch(void* const* d_in, const int* in_sizes, int n_in,
                              void* d_out, int out_size, void* d_ws, size_t ws_size,
                              hipStream_t stream) {
    const float* x   = (const float*)d_in[0];
    const int*   ei  = (const int*)d_in[1];
    const int*   row = ei;
    const int*   col = ei + NE;
    const int*   batch = (const int*)d_in[2];
    const float* w1i = (const float*)d_in[3];
    const float* w1w = (const float*)d_in[4];
    const float* w1r = (const float*)d_in[5];
    const float* w1b = (const float*)d_in[6];
    const float* w2i = (const float*)d_in[7];
    const float* w2w = (const float*)d_in[8];
    const float* w2r = (const float*)d_in[9];
    const float* w2b = (const float*)d_in[10];
    const float* wg  = (const float*)d_in[11];
    const float* bg  = (const float*)d_in[12];
    float* out = (float*)d_out;

    // workspace layout (all 16B-aligned: N*4 bytes is divisible by 16)
    float* A    = (float*)d_ws;                  // [N,48]
    float* B    = A + (size_t)NN * 48;           // [N,48]
    float* R    = B + (size_t)NN * 48;           // [N,48]
    float* h1   = R + (size_t)NN * 48;           // [N,16]
    float* h1p  = h1 + (size_t)NN * 16;          // [N,16]
    float* g1   = h1p + (size_t)NN * 16;         // [N,16]
    float* g1p  = g1 + (size_t)NN * 16;          // [N,16]
    float* g2   = g1p + (size_t)NN * 16;         // [N,16]
    float* dinv = g2 + (size_t)NN * 16;          // [N]
    float* sv   = dinv + NN;                     // [N]
    float* u    = sv + NN;                       // [64]
    int*   cnt  = (int*)(u + 64);                // [N]
    int*   excl = cnt + NN;                      // [N]
    int*   rowptr = excl + NN;                   // [N+1]
    int*   cursor = rowptr + NN + 1;             // [N]
    int*   btot = cursor + NN;                   // [512]
    int*   boff = btot + 512;                    // [512]
    int*   esrc = boff + 512;                    // [E]

    const int T = 256;
    const int NB1 = cdiv(NN, 256);

    // ---- CSR build + dinv + s ----
    hipMemsetAsync(cnt, 0, (size_t)NN * 4, stream);
    k_hist<<<cdiv(NE, T), T, 0, stream>>>(col, cnt, NE);
    k_dinv<<<cdiv(NN, T), T, 0, stream>>>(cnt, dinv, NN);
    k_scan1<<<NB1, 256, 0, stream>>>(cnt, excl, btot, NN);
    k_scan2<<<1, 512, 0, stream>>>(btot, boff, NB1);
    k_scan3<<<cdiv(NN, T), T, 0, stream>>>(excl, boff, rowptr, cursor, NN);
    k_scatter<<<cdiv(NE, T), T, 0, stream>>>(row, col, cursor, esrc, NE);
    k_s<<<cdiv(NN, T), T, 0, stream>>>(rowptr, esrc, dinv, sv, NN);

    // ---- precombined layer-2+head weights (independent, tiny) ----
    k_comb<<<1, 64, 0, stream>>>(w2i, w2w, w2r, w2b, wg, u);

    // ---- layer 1: A = (x@w1i)*dinv, R = x@w1r + b ----
    k_mm1<<<2048, T, 0, stream>>>(x, w1i, w1r, w1b, dinv, (float4*)A, (float4*)R, NN);
    // t=0: B = dinv * relu(prop(A) + R)   (scaled for next prop)
    k_prop<12, 1, 0, 1><<<cdiv((long long)NN * 12, T), T, 0, stream>>>(
        (const float4*)A, (const float4*)R, rowptr, esrc, dinv,
        nullptr, (float4*)B, NN);
    // t=1 agg: A = dinv * prop(B)   (raw prop output, transform applied in post1)
    k_prop<12, 0, 1, 0><<<cdiv((long long)NN * 12, T), T, 0, stream>>>(
        (const float4*)B, nullptr, rowptr, esrc, dinv,
        (float4*)A, nullptr, NN);
    // h1 = mean_k relu(A@w1w + R); h1p = h1*dinv
    k_post1<<<cdiv((long long)NN * 4, T), T, 0, stream>>>(
        (const float4*)A, (const float4*)R, w1w, dinv, (float4*)h1, (float4*)h1p, NN);

    // ---- layer 2 (linearized): g1 = A_n h1, g2 = A_n g1 ----
    k_prop<4, 0, 1, 1><<<cdiv((long long)NN * 4, T), T, 0, stream>>>(
        (const float4*)h1p, nullptr, rowptr, esrc, dinv,
        (float4*)g1, (float4*)g1p, NN);
    k_prop<4, 0, 1, 0><<<cdiv((long long)NN * 4, T), T, 0, stream>>>(
        (const float4*)g1p, nullptr, rowptr, esrc, dinv,
        (float4*)g2, nullptr, NN);

    // ---- score + pool + head ----
    k_initout<<<cdiv(NG, T), T, 0, stream>>>(out, bg, NG);
    k_score<<<cdiv((long long)NN * 4, T), T, 0, stream>>>(
        (const float4*)h1, (const float4*)g1, (const float4*)g2, sv, u, batch, out, NN);
}

// Round 5
// 384.003 us; speedup vs baseline: 3.9606x; 3.9606x over previous
//
#include <hip/hip_runtime.h>

#define NN 100000
#define NE 1200000
#define NG 2048

static inline int cdiv(long long a, int b) { return (int)((a + b - 1) / b); }

// ---------------- CSR build: histogram / dinv / scan / scatter ----------------
__global__ void k_hist(const int* __restrict__ col, int* __restrict__ cnt, int E) {
    int e = blockIdx.x * blockDim.x + threadIdx.x;
    if (e < E) atomicAdd(&cnt[col[e]], 1);
}

__global__ void k_dinv(const int* __restrict__ cnt, float* __restrict__ dinv, int N) {
    int n = blockIdx.x * blockDim.x + threadIdx.x;
    if (n < N) {
        int c = cnt[n];
        dinv[n] = c > 0 ? rsqrtf((float)c) : 0.f;
    }
}

__global__ void k_scan1(const int* __restrict__ cnt, int* __restrict__ excl,
                        int* __restrict__ btot, int N) {
    __shared__ int s[256];
    int tid = threadIdx.x;
    int i = blockIdx.x * 256 + tid;
    int v = (i < N) ? cnt[i] : 0;
    s[tid] = v;
    __syncthreads();
    for (int off = 1; off < 256; off <<= 1) {
        int t = (tid >= off) ? s[tid - off] : 0;
        __syncthreads();
        s[tid] += t;
        __syncthreads();
    }
    if (i < N) excl[i] = s[tid] - v;
    if (tid == 255) btot[blockIdx.x] = s[255];
}

__global__ void k_scan2(const int* __restrict__ btot, int* __restrict__ boff, int NB) {
    __shared__ int s[512];
    int tid = threadIdx.x;
    int v = (tid < NB) ? btot[tid] : 0;
    s[tid] = v;
    __syncthreads();
    for (int off = 1; off < 512; off <<= 1) {
        int t = (tid >= off) ? s[tid - off] : 0;
        __syncthreads();
        s[tid] += t;
        __syncthreads();
    }
    if (tid < NB) boff[tid] = s[tid] - v;
}

__global__ void k_scan3(const int* __restrict__ excl, const int* __restrict__ boff,
                        int* __restrict__ rowptr, int* __restrict__ cursor, int N) {
    int i = blockIdx.x * blockDim.x + threadIdx.x;
    if (i < N) {
        int rp = excl[i] + boff[i >> 8];
        rowptr[i] = rp;
        cursor[i] = rp;
    }
    if (i == 0) rowptr[N] = NE;
}

__global__ void k_scatter(const int* __restrict__ row, const int* __restrict__ col,
                          int* __restrict__ cursor, int* __restrict__ esrc, int E) {
    int e = blockIdx.x * blockDim.x + threadIdx.x;
    if (e < E) {
        int c = col[e];
        int p = atomicAdd(&cursor[c], 1);
        esrc[p] = row[e];
    }
}

// s[n] = dinv[n] * sum_in dinv[r]
__global__ void k_s(const int* __restrict__ rowptr, const int* __restrict__ esrc,
                    const float* __restrict__ dinv, float* __restrict__ s, int N) {
    int n = blockIdx.x * blockDim.x + threadIdx.x;
    if (n >= N) return;
    int beg = rowptr[n], end = rowptr[n + 1];
    float a = 0.f;
    int p = beg;
    for (; p + 3 < end; p += 4) {
        int r0 = esrc[p], r1 = esrc[p + 1], r2 = esrc[p + 2], r3 = esrc[p + 3];
        a += (dinv[r0] + dinv[r1]) + (dinv[r2] + dinv[r3]);
    }
    for (; p < end; ++p) a += dinv[esrc[p]];
    s[n] = a * dinv[n];
}

// ---------------- node-GEMM (R3-proven template, uniform control flow) ----------------
// out[n, k*O+o..o+3] = (BIAS? b[k,o..]:0) + sum_f X[n*F+f]*W[k,f,o..]; SCALE-> *dinv[n]
template <int F, int K, int O, int BIAS, int SCALE>
__global__ void k_mm(const float* __restrict__ X, const float* __restrict__ W,
                     const float* __restrict__ bias, const float* __restrict__ dinv,
                     float4* __restrict__ out4, int N) {
    constexpr int O4 = O / 4;
    constexpr int FC4 = K * O4;
    __shared__ float4 Ws[K * F * O4];
    const float4* W4 = (const float4*)W;
    for (int i = threadIdx.x; i < K * F * O4; i += blockDim.x) Ws[i] = W4[i];
    __syncthreads();
    const int total = N * FC4;
    const int stride = gridDim.x * blockDim.x;
    for (int idx = blockIdx.x * blockDim.x + threadIdx.x; idx < total; idx += stride) {
        int n = idx / FC4;
        int q = idx - n * FC4;
        int k = q / O4;
        int o4 = q - k * O4;
        const float* xp = X + (size_t)n * F;
        const float4* wp = Ws + k * F * O4 + o4;
        float ax, ay, az, aw;
        if (BIAS) {
            float4 b = ((const float4*)bias)[q];
            ax = b.x; ay = b.y; az = b.z; aw = b.w;
        } else {
            ax = 0.f; ay = 0.f; az = 0.f; aw = 0.f;
        }
#pragma unroll
        for (int f = 0; f < F; ++f) {
            float xv = xp[f];
            float4 w = wp[f * O4];
            ax = fmaf(xv, w.x, ax);
            ay = fmaf(xv, w.y, ay);
            az = fmaf(xv, w.z, az);
            aw = fmaf(xv, w.w, aw);
        }
        float4 r;
        if (SCALE) {
            float dn = dinv[n];
            r.x = ax * dn; r.y = ay * dn; r.z = az * dn; r.w = aw * dn;
        } else {
            r.x = ax; r.y = ay; r.z = az; r.w = aw;
        }
        out4[idx] = r;
    }
}

// ---------------- CSR-gather prop, float4, optional root+relu epilogue ----------------
template <int FC4, int HAS_R, int WRITE_RAW, int WRITE_SCALED>
__global__ void k_prop(const float4* __restrict__ src4, const float4* __restrict__ R4,
                       const int* __restrict__ rowptr, const int* __restrict__ esrc,
                       const float* __restrict__ dinv,
                       float4* __restrict__ raw4, float4* __restrict__ scaled4, int N) {
    const int total = N * FC4;
    const int stride = gridDim.x * blockDim.x;
    for (int idx = blockIdx.x * blockDim.x + threadIdx.x; idx < total; idx += stride) {
        int n = idx / FC4;
        int q = idx - n * FC4;
        int beg = rowptr[n], end = rowptr[n + 1];
        float ax = 0.f, ay = 0.f, az = 0.f, aw = 0.f;
        int p = beg;
        for (; p + 3 < end; p += 4) {
            int r0 = esrc[p], r1 = esrc[p + 1], r2 = esrc[p + 2], r3 = esrc[p + 3];
            float4 v0 = src4[(size_t)r0 * FC4 + q];
            float4 v1 = src4[(size_t)r1 * FC4 + q];
            float4 v2 = src4[(size_t)r2 * FC4 + q];
            float4 v3 = src4[(size_t)r3 * FC4 + q];
            ax += (v0.x + v1.x) + (v2.x + v3.x);
            ay += (v0.y + v1.y) + (v2.y + v3.y);
            az += (v0.z + v1.z) + (v2.z + v3.z);
            aw += (v0.w + v1.w) + (v2.w + v3.w);
        }
        for (; p < end; ++p) {
            int r = esrc[p];
            float4 v = src4[(size_t)r * FC4 + q];
            ax += v.x; ay += v.y; az += v.z; aw += v.w;
        }
        float dn = dinv[n];
        float4 v;
        v.x = ax * dn; v.y = ay * dn; v.z = az * dn; v.w = aw * dn;
        if (HAS_R) {
            float4 r = R4[idx];
            v.x = fmaxf(v.x + r.x, 0.f);
            v.y = fmaxf(v.y + r.y, 0.f);
            v.z = fmaxf(v.z + r.z, 0.f);
            v.w = fmaxf(v.w + r.w, 0.f);
        }
        if (WRITE_RAW) raw4[idx] = v;
        if (WRITE_SCALED) {
            float4 sv;
            sv.x = v.x * dn; sv.y = v.y * dn; sv.z = v.z * dn; sv.w = v.w * dn;
            scaled4[idx] = sv;
        }
    }
}

// ---------------- layer-1 t=1 epilogue: h1 = mean_k relu(agg2@w1w[k] + R) ----------------
__global__ void k_post1(const float4* __restrict__ A4, const float4* __restrict__ R4,
                        const float* __restrict__ w1w, const float* __restrict__ dinv,
                        float4* __restrict__ h14, float4* __restrict__ h1p4, int N) {
    __shared__ float4 Ws[192];  // [3][16][4] float4 of w1w[k][i][o]
    const float4* w4 = (const float4*)w1w;
    for (int i = threadIdx.x; i < 192; i += blockDim.x) Ws[i] = w4[i];
    __syncthreads();
    const int total = N * 4;
    const int stride = gridDim.x * blockDim.x;
    for (int idx = blockIdx.x * blockDim.x + threadIdx.x; idx < total; idx += stride) {
        int n = idx >> 2;
        int o4 = idx & 3;
        const float4* ap = A4 + (size_t)n * 12;
        float4 sum = make_float4(0.f, 0.f, 0.f, 0.f);
#pragma unroll
        for (int k = 0; k < 3; ++k) {
            float4 d = R4[(size_t)n * 12 + k * 4 + o4];
#pragma unroll
            for (int i4 = 0; i4 < 4; ++i4) {
                float4 av = ap[k * 4 + i4];
                float4 w0 = Ws[(k * 16 + i4 * 4 + 0) * 4 + o4];
                float4 w1 = Ws[(k * 16 + i4 * 4 + 1) * 4 + o4];
                float4 w2 = Ws[(k * 16 + i4 * 4 + 2) * 4 + o4];
                float4 w3 = Ws[(k * 16 + i4 * 4 + 3) * 4 + o4];
                d.x = fmaf(av.x, w0.x, fmaf(av.y, w1.x, fmaf(av.z, w2.x, fmaf(av.w, w3.x, d.x))));
                d.y = fmaf(av.x, w0.y, fmaf(av.y, w1.y, fmaf(av.z, w2.y, fmaf(av.w, w3.y, d.y))));
                d.z = fmaf(av.x, w0.z, fmaf(av.y, w1.z, fmaf(av.z, w2.z, fmaf(av.w, w3.z, d.z))));
                d.w = fmaf(av.x, w0.w, fmaf(av.y, w1.w, fmaf(av.z, w2.w, fmaf(av.w, w3.w, d.w))));
            }
            d.x = fmaxf(d.x, 0.f); d.y = fmaxf(d.y, 0.f);
            d.z = fmaxf(d.z, 0.f); d.w = fmaxf(d.w, 0.f);
            sum.x += d.x; sum.y += d.y; sum.z += d.z; sum.w += d.w;
        }
        const float third = 1.0f / 3.0f;
        sum.x *= third; sum.y *= third; sum.z *= third; sum.w *= third;
        h14[idx] = sum;
        float dn = dinv[n];
        float4 sp;
        sp.x = sum.x * dn; sp.y = sum.y * dn; sp.z = sum.z * dn; sp.w = sum.w * dn;
        h1p4[idx] = sp;
    }
}

// ---------------- precombine layer-2 + head weights into u-vectors ----------------
// u[0..15]=u0, u[16..31]=u1, u[32..47]=u2, u[48]=c0, u[49]=c1
__global__ void k_comb(const float* __restrict__ w2i, const float* __restrict__ w2w,
                       const float* __restrict__ w2r, const float* __restrict__ b2,
                       const float* __restrict__ wg, float* __restrict__ u) {
    __shared__ float t[3][64];
    int tid = threadIdx.x;  // 64 threads, one wave
    float wgv = wg[tid];
#pragma unroll
    for (int k = 0; k < 3; ++k) {
        float a = 0.f;
        for (int j = 0; j < 64; ++j) a = fmaf(w2w[k * 4096 + tid * 64 + j], wg[j], a);
        t[k][tid] = a;
    }
    __syncthreads();
    float tk0 = t[0][tid], tk1 = t[1][tid], tk2 = t[2][tid];
    const float third = 1.0f / 3.0f;
    // each j: lane-parallel over i=tid, reduce across wave
    for (int j = 0; j < 16; ++j) {
        float wi0 = w2i[j * 64 + tid], wi1 = w2i[1024 + j * 64 + tid], wi2 = w2i[2048 + j * 64 + tid];
        float wr0 = w2r[j * 64 + tid], wr1 = w2r[1024 + j * 64 + tid], wr2 = w2r[2048 + j * 64 + tid];
        float a2 = wi0 * tk0 + wi1 * tk1 + wi2 * tk2;
        float a1 = wr0 * tk0 + wr1 * tk1 + wr2 * tk2;
        float a0 = (wr0 + wr1 + wr2) * wgv;
#pragma unroll
        for (int off = 32; off > 0; off >>= 1) {
            a2 += __shfl_down(a2, off, 64);
            a1 += __shfl_down(a1, off, 64);
            a0 += __shfl_down(a0, off, 64);
        }
        if (tid == 0) {
            u[j] = a0 * third;
            u[16 + j] = a1 * third;
            u[32 + j] = a2 * third;
        }
    }
    float b0 = b2[tid], b1v = b2[64 + tid], b2v = b2[128 + tid];
    float c0 = b0 * tk0 + b1v * tk1 + b2v * tk2;
    float c1 = (b0 + b1v + b2v) * wgv;
#pragma unroll
    for (int off = 32; off > 0; off >>= 1) {
        c0 += __shfl_down(c0, off, 64);
        c1 += __shfl_down(c1, off, 64);
    }
    if (tid == 0) {
        u[48] = c0 * third;
        u[49] = c1 * third;
    }
}

// ---------------- per-node score + pooled head ----------------
__global__ void k_initout(float* __restrict__ out, const float* __restrict__ bg, int G) {
    int g = blockIdx.x * blockDim.x + threadIdx.x;
    if (g < G) out[g] = bg[0];
}

__global__ void k_score(const float4* __restrict__ h14, const float4* __restrict__ g14,
                        const float4* __restrict__ g24, const float* __restrict__ s,
                        const float* __restrict__ u, const int* __restrict__ batch,
                        float* __restrict__ out, int N) {
    int idx = blockIdx.x * blockDim.x + threadIdx.x;
    if (idx >= N * 4) return;
    int n = idx >> 2;
    int j = idx & 3;
    float4 a = h14[idx], b = g14[idx], c = g24[idx];
    float4 u0 = ((const float4*)u)[j];
    float4 u1 = ((const float4*)u)[4 + j];
    float4 u2 = ((const float4*)u)[8 + j];
    float v = a.x * u0.x + a.y * u0.y + a.z * u0.z + a.w * u0.w
            + b.x * u1.x + b.y * u1.y + b.z * u1.z + b.w * u1.w
            + c.x * u2.x + c.y * u2.y + c.z * u2.z + c.w * u2.w;
    v += __shfl_down(v, 2, 4);
    v += __shfl_down(v, 1, 4);
    if (j == 0) {
        v += s[n] * u[48] + u[49];
        atomicAdd(&out[batch[n]], v);
    }
}

extern "C" void kernel_launch(void* const* d_in, const int* in_sizes, int n_in,
                              void* d_out, int out_size, void* d_ws, size_t ws_size,
                              hipStream_t stream) {
    const float* x   = (const float*)d_in[0];
    const int*   ei  = (const int*)d_in[1];
    const int*   row = ei;
    const int*   col = ei + NE;
    const int*   batch = (const int*)d_in[2];
    const float* w1i = (const float*)d_in[3];
    const float* w1w = (const float*)d_in[4];
    const float* w1r = (const float*)d_in[5];
    const float* w1b = (const float*)d_in[6];
    const float* w2i = (const float*)d_in[7];
    const float* w2w = (const float*)d_in[8];
    const float* w2r = (const float*)d_in[9];
    const float* w2b = (const float*)d_in[10];
    const float* wg  = (const float*)d_in[11];
    const float* bg  = (const float*)d_in[12];
    float* out = (float*)d_out;

    float* A    = (float*)d_ws;                  // [N,48]
    float* B    = A + (size_t)NN * 48;           // [N,48]
    float* R    = B + (size_t)NN * 48;           // [N,48]
    float* h1   = R + (size_t)NN * 48;           // [N,16]
    float* h1p  = h1 + (size_t)NN * 16;          // [N,16]
    float* g1   = h1p + (size_t)NN * 16;         // [N,16]
    float* g1p  = g1 + (size_t)NN * 16;          // [N,16]
    float* g2   = g1p + (size_t)NN * 16;         // [N,16]
    float* dinv = g2 + (size_t)NN * 16;          // [N]
    float* sv   = dinv + NN;                     // [N]
    float* u    = sv + NN;                       // [64]
    int*   cnt  = (int*)(u + 64);                // [N]
    int*   excl = cnt + NN;                      // [N]
    int*   rowptr = excl + NN;                   // [N+1]
    int*   cursor = rowptr + NN + 1;             // [N]
    int*   btot = cursor + NN;                   // [512]
    int*   boff = btot + 512;                    // [512]
    int*   esrc = boff + 512;                    // [E]

    const int T = 256;
    const int NB1 = cdiv(NN, 256);

    // ---- CSR build + dinv + s ----
    hipMemsetAsync(cnt, 0, (size_t)NN * 4, stream);
    k_hist<<<cdiv(NE, T), T, 0, stream>>>(col, cnt, NE);
    k_dinv<<<cdiv(NN, T), T, 0, stream>>>(cnt, dinv, NN);
    k_scan1<<<NB1, 256, 0, stream>>>(cnt, excl, btot, NN);
    k_scan2<<<1, 512, 0, stream>>>(btot, boff, NB1);
    k_scan3<<<cdiv(NN, T), T, 0, stream>>>(excl, boff, rowptr, cursor, NN);
    k_scatter<<<cdiv(NE, T), T, 0, stream>>>(row, col, cursor, esrc, NE);
    k_s<<<cdiv(NN, T), T, 0, stream>>>(rowptr, esrc, dinv, sv, NN);

    // ---- precombined layer-2+head weights (tiny) ----
    k_comb<<<1, 64, 0, stream>>>(w2i, w2w, w2r, w2b, wg, u);

    // ---- layer 1 input transforms (two proven-template kernels) ----
    k_mm<75, 3, 16, 0, 1><<<2048, T, 0, stream>>>(x, w1i, nullptr, dinv, (float4*)A, NN);
    k_mm<75, 3, 16, 1, 0><<<2048, T, 0, stream>>>(x, w1r, w1b, nullptr, (float4*)R, NN);

    // t=0: B = dinv * relu(prop(A) + R)
    k_prop<12, 1, 0, 1><<<cdiv((long long)NN * 12, T), T, 0, stream>>>(
        (const float4*)A, (const float4*)R, rowptr, esrc, dinv,
        nullptr, (float4*)B, NN);
    // t=1 agg: A = dinv * prop(B)
    k_prop<12, 0, 1, 0><<<cdiv((long long)NN * 12, T), T, 0, stream>>>(
        (const float4*)B, nullptr, rowptr, esrc, dinv,
        (float4*)A, nullptr, NN);
    // h1 = mean_k relu(A@w1w + R); h1p = h1*dinv
    k_post1<<<cdiv((long long)NN * 4, T), T, 0, stream>>>(
        (const float4*)A, (const float4*)R, w1w, dinv, (float4*)h1, (float4*)h1p, NN);

    // ---- layer 2 (linearized): g1 = A_n h1, g2 = A_n g1 ----
    k_prop<4, 0, 1, 1><<<cdiv((long long)NN * 4, T), T, 0, stream>>>(
        (const float4*)h1p, nullptr, rowptr, esrc, dinv,
        (float4*)g1, (float4*)g1p, NN);
    k_prop<4, 0, 1, 0><<<cdiv((long long)NN * 4, T), T, 0, stream>>>(
        (const float4*)g1p, nullptr, rowptr, esrc, dinv,
        (float4*)g2, nullptr, NN);

    // ---- score + pool + head ----
    k_initout<<<cdiv(NG, T), T, 0, stream>>>(out, bg, NG);
    k_score<<<cdiv((long long)NN * 4, T), T, 0, stream>>>(
        (const float4*)h1, (const float4*)g1, (const float4*)g2, sv, u, batch, out, NN);
}

// Round 6
// 365.237 us; speedup vs baseline: 4.1640x; 1.0514x over previous
//
#include <hip/hip_runtime.h>

#define NN 100000
#define NE 1200000
#define NG 2048
#define ESZ (NE + 3 * NN)   // padded CSR capacity

static inline int cdiv(long long a, int b) { return (int)((a + b - 1) / b); }

// ---------------- init: zero cnt, sentinel-fill esrc, zero sentinel rows ----------------
__global__ void k_init(int* __restrict__ cnt, int* __restrict__ esrc,
                       float4* __restrict__ A4, float4* __restrict__ B4,
                       float4* __restrict__ h1p4, float4* __restrict__ g1p4) {
    int gtid = blockIdx.x * blockDim.x + threadIdx.x;
    int gstride = gridDim.x * blockDim.x;
    for (int i = gtid; i < ESZ; i += gstride) esrc[i] = NN;
    for (int i = gtid; i < NN; i += gstride) cnt[i] = 0;
    float4 z = make_float4(0.f, 0.f, 0.f, 0.f);
    if (gtid < 12) {
        A4[(size_t)NN * 12 + gtid] = z;
        B4[(size_t)NN * 12 + gtid] = z;
    } else if (gtid < 16) {
        h1p4[(size_t)NN * 4 + (gtid - 12)] = z;
        g1p4[(size_t)NN * 4 + (gtid - 12)] = z;
    }
}

// ---------------- CSR build ----------------
__global__ void k_hist(const int* __restrict__ col, int* __restrict__ cnt, int E) {
    int e = blockIdx.x * blockDim.x + threadIdx.x;
    if (e < E) atomicAdd(&cnt[col[e]], 1);
}

// scan of PADDED counts; also emits dinv from real counts
__global__ void k_scan1(const int* __restrict__ cnt, float* __restrict__ dinv,
                        int* __restrict__ excl, int* __restrict__ btot, int N) {
    __shared__ int s[256];
    int tid = threadIdx.x;
    int i = blockIdx.x * 256 + tid;
    int c = (i < N) ? cnt[i] : 0;
    if (i < N) dinv[i] = c > 0 ? rsqrtf((float)c) : 0.f;
    int v = (c + 3) & ~3;   // padded count
    s[tid] = v;
    __syncthreads();
    for (int off = 1; off < 256; off <<= 1) {
        int t = (tid >= off) ? s[tid - off] : 0;
        __syncthreads();
        s[tid] += t;
        __syncthreads();
    }
    if (i < N) excl[i] = s[tid] - v;
    if (tid == 255) btot[blockIdx.x] = s[255];
}

__global__ void k_scan2(const int* __restrict__ btot, int* __restrict__ boff, int NB) {
    __shared__ int s[512];
    int tid = threadIdx.x;
    int v = (tid < NB) ? btot[tid] : 0;
    s[tid] = v;
    __syncthreads();
    for (int off = 1; off < 512; off <<= 1) {
        int t = (tid >= off) ? s[tid - off] : 0;
        __syncthreads();
        s[tid] += t;
        __syncthreads();
    }
    if (tid < NB) boff[tid] = s[tid] - v;
    if (tid == NB - 1) boff[NB] = s[tid];   // grand total (padded)
}

__global__ void k_scan3(const int* __restrict__ excl, const int* __restrict__ boff,
                        int* __restrict__ rowptr, int* __restrict__ cursor,
                        float* __restrict__ dinv, int N, int NB) {
    int i = blockIdx.x * blockDim.x + threadIdx.x;
    if (i < N) {
        int rp = excl[i] + boff[i >> 8];
        rowptr[i] = rp;
        cursor[i] = rp;
    }
    if (i == 0) {
        rowptr[N] = boff[NB];
        dinv[N] = 0.f;     // sentinel
    }
}

__global__ void k_scatter(const int* __restrict__ row, const int* __restrict__ col,
                          int* __restrict__ cursor, int* __restrict__ esrc, int E) {
    int e = blockIdx.x * blockDim.x + threadIdx.x;
    if (e < E) {
        int c = col[e];
        int p = atomicAdd(&cursor[c], 1);
        esrc[p] = row[e];
    }
}

// ---------------- node-GEMM (proven uniform template) ----------------
template <int F, int K, int O, int BIAS, int SCALE>
__global__ void k_mm(const float* __restrict__ X, const float* __restrict__ W,
                     const float* __restrict__ bias, const float* __restrict__ dinv,
                     float4* __restrict__ out4, int N) {
    constexpr int O4 = O / 4;
    constexpr int FC4 = K * O4;
    __shared__ float4 Ws[K * F * O4];
    const float4* W4 = (const float4*)W;
    for (int i = threadIdx.x; i < K * F * O4; i += blockDim.x) Ws[i] = W4[i];
    __syncthreads();
    const int total = N * FC4;
    const int stride = gridDim.x * blockDim.x;
    for (int idx = blockIdx.x * blockDim.x + threadIdx.x; idx < total; idx += stride) {
        int n = idx / FC4;
        int q = idx - n * FC4;
        int k = q / O4;
        int o4 = q - k * O4;
        const float* xp = X + (size_t)n * F;
        const float4* wp = Ws + k * F * O4 + o4;
        float ax, ay, az, aw;
        if (BIAS) {
            float4 b = ((const float4*)bias)[q];
            ax = b.x; ay = b.y; az = b.z; aw = b.w;
        } else {
            ax = 0.f; ay = 0.f; az = 0.f; aw = 0.f;
        }
#pragma unroll
        for (int f = 0; f < F; ++f) {
            float xv = xp[f];
            float4 w = wp[f * O4];
            ax = fmaf(xv, w.x, ax);
            ay = fmaf(xv, w.y, ay);
            az = fmaf(xv, w.z, az);
            aw = fmaf(xv, w.w, aw);
        }
        float4 r;
        if (SCALE) {
            float dn = dinv[n];
            r.x = ax * dn; r.y = ay * dn; r.z = az * dn; r.w = aw * dn;
        } else {
            r.x = ax; r.y = ay; r.z = az; r.w = aw;
        }
        out4[idx] = r;
    }
}

// ---------------- 48-wide CSR prop (padded, int4 esrc), optional R+relu, optional s ----------------
template <int HAS_R, int COMPUTE_S, int WRITE_RAW, int WRITE_SCALED>
__global__ void k_prop48(const float4* __restrict__ src4, const float4* __restrict__ R4,
                         const int* __restrict__ rowptr, const int* __restrict__ esrc,
                         const float* __restrict__ dinv, float* __restrict__ sv,
                         float4* __restrict__ raw4, float4* __restrict__ scaled4, int N) {
    const int total = N * 12;
    const int stride = gridDim.x * blockDim.x;
    for (int idx = blockIdx.x * blockDim.x + threadIdx.x; idx < total; idx += stride) {
        int n = idx / 12;
        int q = idx - n * 12;
        int beg = rowptr[n], end = rowptr[n + 1];
        float ax = 0.f, ay = 0.f, az = 0.f, aw = 0.f;
        float sd = 0.f;
        for (int p = beg; p < end; p += 4) {
            int4 e = *(const int4*)(esrc + p);
            float4 v0 = src4[(size_t)e.x * 12 + q];
            float4 v1 = src4[(size_t)e.y * 12 + q];
            float4 v2 = src4[(size_t)e.z * 12 + q];
            float4 v3 = src4[(size_t)e.w * 12 + q];
            ax += (v0.x + v1.x) + (v2.x + v3.x);
            ay += (v0.y + v1.y) + (v2.y + v3.y);
            az += (v0.z + v1.z) + (v2.z + v3.z);
            aw += (v0.w + v1.w) + (v2.w + v3.w);
            if (COMPUTE_S) {
                if (q == 0)
                    sd += (dinv[e.x] + dinv[e.y]) + (dinv[e.z] + dinv[e.w]);
            }
        }
        float dn = dinv[n];
        float4 v;
        v.x = ax * dn; v.y = ay * dn; v.z = az * dn; v.w = aw * dn;
        if (HAS_R) {
            float4 r = R4[idx];
            v.x = fmaxf(v.x + r.x, 0.f);
            v.y = fmaxf(v.y + r.y, 0.f);
            v.z = fmaxf(v.z + r.z, 0.f);
            v.w = fmaxf(v.w + r.w, 0.f);
        }
        if (WRITE_RAW) raw4[idx] = v;
        if (WRITE_SCALED) {
            float4 s4;
            s4.x = v.x * dn; s4.y = v.y * dn; s4.z = v.z * dn; s4.w = v.w * dn;
            scaled4[idx] = s4;
        }
        if (COMPUTE_S) {
            if (q == 0) sv[n] = sd * dn;
        }
    }
}

// ---------------- layer-1 t=1 epilogue: h1p = dinv*mean_k relu(agg@w1w+R); z0 = h1.u0 ----------------
__global__ void k_post1(const float4* __restrict__ A4, const float4* __restrict__ R4,
                        const float* __restrict__ w1w, const float* __restrict__ dinv,
                        const float* __restrict__ u,
                        float4* __restrict__ h1p4, float* __restrict__ z0, int N) {
    __shared__ float4 Ws[192];  // [3][16][4] float4 of w1w[k][i][o]
    const float4* w4 = (const float4*)w1w;
    for (int i = threadIdx.x; i < 192; i += blockDim.x) Ws[i] = w4[i];
    __syncthreads();
    const int total = N * 4;
    const int stride = gridDim.x * blockDim.x;
    for (int idx = blockIdx.x * blockDim.x + threadIdx.x; idx < total; idx += stride) {
        int n = idx >> 2;
        int o4 = idx & 3;
        const float4* ap = A4 + (size_t)n * 12;
        float4 sum = make_float4(0.f, 0.f, 0.f, 0.f);
#pragma unroll
        for (int k = 0; k < 3; ++k) {
            float4 d = R4[(size_t)n * 12 + k * 4 + o4];
#pragma unroll
            for (int i4 = 0; i4 < 4; ++i4) {
                float4 av = ap[k * 4 + i4];
                float4 w0 = Ws[(k * 16 + i4 * 4 + 0) * 4 + o4];
                float4 w1 = Ws[(k * 16 + i4 * 4 + 1) * 4 + o4];
                float4 w2 = Ws[(k * 16 + i4 * 4 + 2) * 4 + o4];
                float4 w3 = Ws[(k * 16 + i4 * 4 + 3) * 4 + o4];
                d.x = fmaf(av.x, w0.x, fmaf(av.y, w1.x, fmaf(av.z, w2.x, fmaf(av.w, w3.x, d.x))));
                d.y = fmaf(av.x, w0.y, fmaf(av.y, w1.y, fmaf(av.z, w2.y, fmaf(av.w, w3.y, d.y))));
                d.z = fmaf(av.x, w0.z, fmaf(av.y, w1.z, fmaf(av.z, w2.z, fmaf(av.w, w3.z, d.z))));
                d.w = fmaf(av.x, w0.w, fmaf(av.y, w1.w, fmaf(av.z, w2.w, fmaf(av.w, w3.w, d.w))));
            }
            d.x = fmaxf(d.x, 0.f); d.y = fmaxf(d.y, 0.f);
            d.z = fmaxf(d.z, 0.f); d.w = fmaxf(d.w, 0.f);
            sum.x += d.x; sum.y += d.y; sum.z += d.z; sum.w += d.w;
        }
        const float third = 1.0f / 3.0f;
        sum.x *= third; sum.y *= third; sum.z *= third; sum.w *= third;
        float dn = dinv[n];
        float4 sp;
        sp.x = sum.x * dn; sp.y = sum.y * dn; sp.z = sum.z * dn; sp.w = sum.w * dn;
        h1p4[idx] = sp;
        // z0 partial: dot(h1 quad, u0 quad), reduce over the 4 lanes of this node
        float4 u0q = ((const float4*)u)[o4];
        float part = sum.x * u0q.x + sum.y * u0q.y + sum.z * u0q.z + sum.w * u0q.w;
        part += __shfl_down(part, 2, 4);
        part += __shfl_down(part, 1, 4);
        if (o4 == 0) z0[n] = part;
    }
}

// ---------------- prop16 #1: g1 = A_n h1; writes g1p (scaled) and z1 = g1.u1 ----------------
__global__ void k_prop16z(const float4* __restrict__ h1p4,
                          const int* __restrict__ rowptr, const int* __restrict__ esrc,
                          const float* __restrict__ dinv, const float* __restrict__ u,
                          float4* __restrict__ g1p4, float* __restrict__ z1, int N) {
    const int total = N * 4;
    const int stride = gridDim.x * blockDim.x;
    for (int idx = blockIdx.x * blockDim.x + threadIdx.x; idx < total; idx += stride) {
        int n = idx >> 2;
        int q = idx & 3;
        int beg = rowptr[n], end = rowptr[n + 1];
        float ax = 0.f, ay = 0.f, az = 0.f, aw = 0.f;
        for (int p = beg; p < end; p += 4) {
            int4 e = *(const int4*)(esrc + p);
            float4 v0 = h1p4[(size_t)e.x * 4 + q];
            float4 v1 = h1p4[(size_t)e.y * 4 + q];
            float4 v2 = h1p4[(size_t)e.z * 4 + q];
            float4 v3 = h1p4[(size_t)e.w * 4 + q];
            ax += (v0.x + v1.x) + (v2.x + v3.x);
            ay += (v0.y + v1.y) + (v2.y + v3.y);
            az += (v0.z + v1.z) + (v2.z + v3.z);
            aw += (v0.w + v1.w) + (v2.w + v3.w);
        }
        float dn = dinv[n];
        float4 v;
        v.x = ax * dn; v.y = ay * dn; v.z = az * dn; v.w = aw * dn;
        float4 s4;
        s4.x = v.x * dn; s4.y = v.y * dn; s4.z = v.z * dn; s4.w = v.w * dn;
        g1p4[idx] = s4;
        float4 u1q = ((const float4*)u)[4 + q];
        float part = v.x * u1q.x + v.y * u1q.y + v.z * u1q.z + v.w * u1q.w;
        part += __shfl_down(part, 2, 4);
        part += __shfl_down(part, 1, 4);
        if (q == 0) z1[n] = part;
    }
}

// ---------------- prop16 #2 fused with score/pool: g2 in-register ----------------
__global__ void k_score(const float4* __restrict__ g1p4,
                        const int* __restrict__ rowptr, const int* __restrict__ esrc,
                        const float* __restrict__ dinv, const float* __restrict__ u,
                        const float* __restrict__ z0, const float* __restrict__ z1,
                        const float* __restrict__ sv, const int* __restrict__ batch,
                        float* __restrict__ out, int N) {
    const int total = N * 4;
    const int stride = gridDim.x * blockDim.x;
    for (int idx = blockIdx.x * blockDim.x + threadIdx.x; idx < total; idx += stride) {
        int n = idx >> 2;
        int q = idx & 3;
        int beg = rowptr[n], end = rowptr[n + 1];
        float ax = 0.f, ay = 0.f, az = 0.f, aw = 0.f;
        for (int p = beg; p < end; p += 4) {
            int4 e = *(const int4*)(esrc + p);
            float4 v0 = g1p4[(size_t)e.x * 4 + q];
            float4 v1 = g1p4[(size_t)e.y * 4 + q];
            float4 v2 = g1p4[(size_t)e.z * 4 + q];
            float4 v3 = g1p4[(size_t)e.w * 4 + q];
            ax += (v0.x + v1.x) + (v2.x + v3.x);
            ay += (v0.y + v1.y) + (v2.y + v3.y);
            az += (v0.z + v1.z) + (v2.z + v3.z);
            aw += (v0.w + v1.w) + (v2.w + v3.w);
        }
        float dn = dinv[n];
        float4 u2q = ((const float4*)u)[8 + q];
        float part = (ax * dn) * u2q.x + (ay * dn) * u2q.y +
                     (az * dn) * u2q.z + (aw * dn) * u2q.w;
        part += __shfl_down(part, 2, 4);
        part += __shfl_down(part, 1, 4);
        if (q == 0) {
            float v = part + z0[n] + z1[n] + sv[n] * u[48] + u[49];
            atomicAdd(&out[batch[n]], v);
        }
    }
}

// ---------------- precombine layer-2+head weights; blocks 1..8 init out ----------------
__global__ void k_comb(const float* __restrict__ w2i, const float* __restrict__ w2w,
                       const float* __restrict__ w2r, const float* __restrict__ b2,
                       const float* __restrict__ wg, const float* __restrict__ bg,
                       float* __restrict__ u, float* __restrict__ out) {
    if (blockIdx.x > 0) {
        int g = (blockIdx.x - 1) * 256 + threadIdx.x;
        if (g < NG) out[g] = bg[0];
        return;
    }
    __shared__ float t[3][64];
    int tid = threadIdx.x;
    if (tid < 64) {
        float wgv = wg[tid];
#pragma unroll
        for (int k = 0; k < 3; ++k) {
            float a = 0.f;
            for (int j = 0; j < 64; ++j) a = fmaf(w2w[k * 4096 + tid * 64 + j], wg[j], a);
            t[k][tid] = a;
        }
        (void)wgv;
    }
    __syncthreads();
    if (tid < 64) {
        float wgv = wg[tid];
        float tk0 = t[0][tid], tk1 = t[1][tid], tk2 = t[2][tid];
        const float third = 1.0f / 3.0f;
        for (int j = 0; j < 16; ++j) {
            float wi0 = w2i[j * 64 + tid], wi1 = w2i[1024 + j * 64 + tid], wi2 = w2i[2048 + j * 64 + tid];
            float wr0 = w2r[j * 64 + tid], wr1 = w2r[1024 + j * 64 + tid], wr2 = w2r[2048 + j * 64 + tid];
            float a2 = wi0 * tk0 + wi1 * tk1 + wi2 * tk2;
            float a1 = wr0 * tk0 + wr1 * tk1 + wr2 * tk2;
            float a0 = (wr0 + wr1 + wr2) * wgv;
#pragma unroll
            for (int off = 32; off > 0; off >>= 1) {
                a2 += __shfl_down(a2, off, 64);
                a1 += __shfl_down(a1, off, 64);
                a0 += __shfl_down(a0, off, 64);
            }
            if (tid == 0) {
                u[j] = a0 * third;
                u[16 + j] = a1 * third;
                u[32 + j] = a2 * third;
            }
        }
        float b0 = b2[tid], b1v = b2[64 + tid], b2v = b2[128 + tid];
        float c0 = b0 * tk0 + b1v * tk1 + b2v * tk2;
        float c1 = (b0 + b1v + b2v) * wgv;
#pragma unroll
        for (int off = 32; off > 0; off >>= 1) {
            c0 += __shfl_down(c0, off, 64);
            c1 += __shfl_down(c1, off, 64);
        }
        if (tid == 0) {
            u[48] = c0 * third;
            u[49] = c1 * third;
        }
    }
}

extern "C" void kernel_launch(void* const* d_in, const int* in_sizes, int n_in,
                              void* d_out, int out_size, void* d_ws, size_t ws_size,
                              hipStream_t stream) {
    const float* x   = (const float*)d_in[0];
    const int*   ei  = (const int*)d_in[1];
    const int*   row = ei;
    const int*   col = ei + NE;
    const int*   batch = (const int*)d_in[2];
    const float* w1i = (const float*)d_in[3];
    const float* w1w = (const float*)d_in[4];
    const float* w1r = (const float*)d_in[5];
    const float* w1b = (const float*)d_in[6];
    const float* w2i = (const float*)d_in[7];
    const float* w2w = (const float*)d_in[8];
    const float* w2r = (const float*)d_in[9];
    const float* w2b = (const float*)d_in[10];
    const float* wg  = (const float*)d_in[11];
    const float* bg  = (const float*)d_in[12];
    float* out = (float*)d_out;

    // workspace layout (every segment 16B-aligned; sizes in floats/ints)
    float* A    = (float*)d_ws;                      // [N+1, 48]
    float* B    = A + (size_t)(NN + 1) * 48;         // [N+1, 48]
    float* R    = B + (size_t)(NN + 1) * 48;         // [N, 48]
    float* h1p  = R + (size_t)NN * 48;               // [N+1, 16]
    float* g1p  = h1p + (size_t)(NN + 1) * 16;       // [N+1, 16]
    float* dinv = g1p + (size_t)(NN + 1) * 16;       // [N+1] (pad to 100004)
    float* sv   = dinv + 100004;                     // [N]
    float* z0   = sv + NN;                           // [N]
    float* z1   = z0 + NN;                           // [N]
    float* u    = z1 + NN;                           // [64]
    int*   cnt  = (int*)(u + 64);                    // [N]
    int*   excl = cnt + NN;                          // [N]
    int*   rowptr = excl + NN;                       // [N+1] (pad to 100004)
    int*   cursor = rowptr + 100004;                 // [N]
    int*   btot = cursor + NN;                       // [512]
    int*   boff = btot + 512;                        // [512]
    int*   esrc = boff + 512;                        // [ESZ]

    const int T = 256;
    const int NB1 = cdiv(NN, 256);   // 391

    // ---- init (cnt=0, esrc=sentinel, sentinel rows=0) ----
    k_init<<<2048, T, 0, stream>>>(cnt, esrc, (float4*)A, (float4*)B,
                                   (float4*)h1p, (float4*)g1p);
    // ---- CSR build (padded) + dinv ----
    k_hist<<<cdiv(NE, T), T, 0, stream>>>(col, cnt, NE);
    k_scan1<<<NB1, 256, 0, stream>>>(cnt, dinv, excl, btot, NN);
    k_scan2<<<1, 512, 0, stream>>>(btot, boff, NB1);
    k_scan3<<<cdiv(NN, T), T, 0, stream>>>(excl, boff, rowptr, cursor, dinv, NN, NB1);
    k_scatter<<<cdiv(NE, T), T, 0, stream>>>(row, col, cursor, esrc, NE);

    // ---- precombined layer-2+head weights + out init ----
    k_comb<<<9, T, 0, stream>>>(w2i, w2w, w2r, w2b, wg, bg, u, out);

    // ---- layer 1 input transforms ----
    k_mm<75, 3, 16, 0, 1><<<2048, T, 0, stream>>>(x, w1i, nullptr, dinv, (float4*)A, NN);
    k_mm<75, 3, 16, 1, 0><<<2048, T, 0, stream>>>(x, w1r, w1b, nullptr, (float4*)R, NN);

    // t=0: B = dinv * relu(prop(A) + R); also sv[n]
    k_prop48<1, 1, 0, 1><<<cdiv((long long)NN * 12, T), T, 0, stream>>>(
        (const float4*)A, (const float4*)R, rowptr, esrc, dinv, sv,
        nullptr, (float4*)B, NN);
    // t=1 agg: A = dinv * prop(B)
    k_prop48<0, 0, 1, 0><<<cdiv((long long)NN * 12, T), T, 0, stream>>>(
        (const float4*)B, nullptr, rowptr, esrc, dinv, nullptr,
        (float4*)A, nullptr, NN);
    // h1p = dinv*mean_k relu(A@w1w + R); z0 = h1.u0
    k_post1<<<cdiv((long long)NN * 4, T), T, 0, stream>>>(
        (const float4*)A, (const float4*)R, w1w, dinv, u, (float4*)h1p, z0, NN);

    // ---- layer 2 (linearized): g1p + z1, then fused g2+score+pool ----
    k_prop16z<<<cdiv((long long)NN * 4, T), T, 0, stream>>>(
        (const float4*)h1p, rowptr, esrc, dinv, u, (float4*)g1p, z1, NN);
    k_score<<<cdiv((long long)NN * 4, T), T, 0, stream>>>(
        (const float4*)g1p, rowptr, esrc, dinv, u, z0, z1, sv, batch, out, NN);
}

// Round 7
// 321.462 us; speedup vs baseline: 4.7311x; 1.1362x over previous
//
#include <hip/hip_runtime.h>

#define NN 100000
#define NE 1200000
#define NG 2048
#define NBK 391           // cdiv(NN,256) buckets of 256 nodes
#define ESZ (NE + 3 * NN) // padded CSR capacity
#define STAGECAP 10240    // LDS stage entries per bucket (40KB)

static inline int cdiv(long long a, int b) { return (int)((a + b - 1) / b); }

// ---------------- init: zero cnt + sentinel node rows ----------------
__global__ void k_init(int* __restrict__ cnt,
                       float4* __restrict__ A4, float4* __restrict__ B4,
                       float4* __restrict__ h1p4, float4* __restrict__ g1p4) {
    int gtid = blockIdx.x * blockDim.x + threadIdx.x;
    int gstride = gridDim.x * blockDim.x;
    for (int i = gtid; i < NN; i += gstride) cnt[i] = 0;
    float4 z = make_float4(0.f, 0.f, 0.f, 0.f);
    if (gtid < 12) {
        A4[(size_t)NN * 12 + gtid] = z;
        B4[(size_t)NN * 12 + gtid] = z;
    } else if (gtid < 16) {
        h1p4[(size_t)NN * 4 + (gtid - 12)] = z;
        g1p4[(size_t)NN * 4 + (gtid - 12)] = z;
    }
}

// ---------------- per-node histogram ----------------
__global__ void k_hist(const int* __restrict__ col, int* __restrict__ cnt, int E) {
    int e = blockIdx.x * blockDim.x + threadIdx.x;
    if (e < E) atomicAdd(&cnt[col[e]], 1);
}

// scan of packed (padded<<16 | raw) counts per 256-node bucket; emits dinv,
// LOCAL padded excl, and packed bucket totals
__global__ void k_scan1(const int* __restrict__ cnt, float* __restrict__ dinv,
                        int* __restrict__ excl, int* __restrict__ btot, int N) {
    __shared__ int s[256];
    int tid = threadIdx.x;
    int i = blockIdx.x * 256 + tid;
    int c = (i < N) ? cnt[i] : 0;
    if (i < N) dinv[i] = c > 0 ? rsqrtf((float)c) : 0.f;
    int v = (((c + 3) & ~3) << 16) | c;
    s[tid] = v;
    __syncthreads();
    for (int off = 1; off < 256; off <<= 1) {
        int t = (tid >= off) ? s[tid - off] : 0;
        __syncthreads();
        s[tid] += t;
        __syncthreads();
    }
    if (i < N) excl[i] = (s[tid] - v) >> 16;   // local padded offset in bucket
    if (tid == 255) btot[blockIdx.x] = s[255]; // packed totals
}

// dual scan of bucket totals: boff (padded, global esrc offsets), qoff (raw, pairs offsets)
__global__ void k_scan2(const int* __restrict__ btot, int* __restrict__ boff,
                        int* __restrict__ qoff, int NB) {
    __shared__ int s[512];
    int tid = threadIdx.x;
    int p = (tid < NB) ? btot[tid] : 0;
    int vp = p >> 16, vr = p & 0xFFFF;
    s[tid] = vp;
    __syncthreads();
    for (int off = 1; off < 512; off <<= 1) {
        int t = (tid >= off) ? s[tid - off] : 0;
        __syncthreads();
        s[tid] += t;
        __syncthreads();
    }
    if (tid < NB) boff[tid] = s[tid] - vp;
    if (tid == NB - 1) boff[NB] = s[tid];
    __syncthreads();
    s[tid] = vr;
    __syncthreads();
    for (int off = 1; off < 512; off <<= 1) {
        int t = (tid >= off) ? s[tid - off] : 0;
        __syncthreads();
        s[tid] += t;
        __syncthreads();
    }
    if (tid < NB) qoff[tid] = s[tid] - vr;
    if (tid == NB - 1) qoff[NB] = s[tid];
}

// rowptr = local excl + bucket base; init bucket cursors; sentinel dinv
__global__ void k_scan3(const int* __restrict__ excl, const int* __restrict__ boff,
                        const int* __restrict__ qoff, int* __restrict__ rowptr,
                        int* __restrict__ bcur, float* __restrict__ dinv, int N) {
    int i = blockIdx.x * blockDim.x + threadIdx.x;
    if (i < N) rowptr[i] = excl[i] + boff[i >> 8];
    if (i < NBK) bcur[i] = qoff[i];
    if (i == 0) {
        rowptr[N] = boff[NBK];
        dinv[N] = 0.f;   // sentinel
    }
}

// ---------------- phase 1: partition edges bucket-major into pairs ----------------
__global__ __launch_bounds__(256) void k_part(const int* __restrict__ row,
                                              const int* __restrict__ col,
                                              int* __restrict__ bcur,
                                              int* __restrict__ pairs, int E) {
    __shared__ int hcnt[NBK];
    __shared__ int hbase[NBK];
    int chunk = (E + gridDim.x - 1) / gridDim.x;
    int beg = blockIdx.x * chunk;
    int end = min(E, beg + chunk);
    for (int j = threadIdx.x; j < NBK; j += 256) hcnt[j] = 0;
    __syncthreads();
    for (int e = beg + threadIdx.x; e < end; e += 256)
        atomicAdd(&hcnt[col[e] >> 8], 1);
    __syncthreads();
    for (int j = threadIdx.x; j < NBK; j += 256) {
        int c = hcnt[j];
        hbase[j] = c > 0 ? atomicAdd(&bcur[j], c) : 0;
        hcnt[j] = 0;
    }
    __syncthreads();
    for (int e = beg + threadIdx.x; e < end; e += 256) {
        int cc = col[e];
        int b = cc >> 8;
        int r = atomicAdd(&hcnt[b], 1);
        pairs[hbase[b] + r] = ((cc & 255) << 17) | row[e];
    }
}

// ---------------- phase 2: per-bucket LDS-staged scatter, coalesced flush ----------------
__global__ __launch_bounds__(256) void k_bucket(const int* __restrict__ pairs,
                                                const int* __restrict__ qoff,
                                                const int* __restrict__ boff,
                                                const int* __restrict__ excl,
                                                const int* __restrict__ rowptr,
                                                int* __restrict__ esrc, int N) {
    __shared__ int stage[STAGECAP];
    __shared__ int lcur[256];
    int b = blockIdx.x;
    int base = b << 8;
    int nn = min(256, N - base);
    int segbase = boff[b];
    int padded = boff[b + 1] - segbase;
    int qb = qoff[b], qe = qoff[b + 1];
    int tid = threadIdx.x;
    if (padded <= STAGECAP) {
        for (int i = tid; i < padded; i += 256) stage[i] = N;  // sentinel
        if (tid < nn) lcur[tid] = excl[base + tid];
        __syncthreads();
        for (int p = qb + tid; p < qe; p += 256) {
            int v = pairs[p];
            int cl = v >> 17, r = v & 0x1FFFF;
            int pos = atomicAdd(&lcur[cl], 1);
            stage[pos] = r;
        }
        __syncthreads();
        for (int i = tid; i < padded; i += 256) esrc[segbase + i] = stage[i];
    } else {  // safety fallback (never expected)
        for (int i = tid; i < padded; i += 256) esrc[segbase + i] = N;
        if (tid < nn) lcur[tid] = rowptr[base + tid];
        __syncthreads();
        for (int p = qb + tid; p < qe; p += 256) {
            int v = pairs[p];
            int cl = v >> 17, r = v & 0x1FFFF;
            int pos = atomicAdd(&lcur[cl], 1);
            esrc[pos] = r;
        }
    }
}

// ---------------- node-GEMM (proven uniform template) ----------------
template <int F, int K, int O, int BIAS, int SCALE>
__global__ void k_mm(const float* __restrict__ X, const float* __restrict__ W,
                     const float* __restrict__ bias, const float* __restrict__ dinv,
                     float4* __restrict__ out4, int N) {
    constexpr int O4 = O / 4;
    constexpr int FC4 = K * O4;
    __shared__ float4 Ws[K * F * O4];
    const float4* W4 = (const float4*)W;
    for (int i = threadIdx.x; i < K * F * O4; i += blockDim.x) Ws[i] = W4[i];
    __syncthreads();
    const int total = N * FC4;
    const int stride = gridDim.x * blockDim.x;
    for (int idx = blockIdx.x * blockDim.x + threadIdx.x; idx < total; idx += stride) {
        int n = idx / FC4;
        int q = idx - n * FC4;
        int k = q / O4;
        int o4 = q - k * O4;
        const float* xp = X + (size_t)n * F;
        const float4* wp = Ws + k * F * O4 + o4;
        float ax, ay, az, aw;
        if (BIAS) {
            float4 b = ((const float4*)bias)[q];
            ax = b.x; ay = b.y; az = b.z; aw = b.w;
        } else {
            ax = 0.f; ay = 0.f; az = 0.f; aw = 0.f;
        }
#pragma unroll
        for (int f = 0; f < F; ++f) {
            float xv = xp[f];
            float4 w = wp[f * O4];
            ax = fmaf(xv, w.x, ax);
            ay = fmaf(xv, w.y, ay);
            az = fmaf(xv, w.z, az);
            aw = fmaf(xv, w.w, aw);
        }
        float4 r;
        if (SCALE) {
            float dn = dinv[n];
            r.x = ax * dn; r.y = ay * dn; r.z = az * dn; r.w = aw * dn;
        } else {
            r.x = ax; r.y = ay; r.z = az; r.w = aw;
        }
        out4[idx] = r;
    }
}

// ---------------- 48-wide CSR prop (padded, int4 esrc), optional R+relu, optional s ----------------
template <int HAS_R, int COMPUTE_S, int WRITE_RAW, int WRITE_SCALED>
__global__ void k_prop48(const float4* __restrict__ src4, const float4* __restrict__ R4,
                         const int* __restrict__ rowptr, const int* __restrict__ esrc,
                         const float* __restrict__ dinv, float* __restrict__ sv,
                         float4* __restrict__ raw4, float4* __restrict__ scaled4, int N) {
    const int total = N * 12;
    const int stride = gridDim.x * blockDim.x;
    for (int idx = blockIdx.x * blockDim.x + threadIdx.x; idx < total; idx += stride) {
        int n = idx / 12;
        int q = idx - n * 12;
        int beg = rowptr[n], end = rowptr[n + 1];
        float ax = 0.f, ay = 0.f, az = 0.f, aw = 0.f;
        float sd = 0.f;
        for (int p = beg; p < end; p += 4) {
            int4 e = *(const int4*)(esrc + p);
            float4 v0 = src4[(size_t)e.x * 12 + q];
            float4 v1 = src4[(size_t)e.y * 12 + q];
            float4 v2 = src4[(size_t)e.z * 12 + q];
            float4 v3 = src4[(size_t)e.w * 12 + q];
            ax += (v0.x + v1.x) + (v2.x + v3.x);
            ay += (v0.y + v1.y) + (v2.y + v3.y);
            az += (v0.z + v1.z) + (v2.z + v3.z);
            aw += (v0.w + v1.w) + (v2.w + v3.w);
            if (COMPUTE_S) {
                if (q == 0)
                    sd += (dinv[e.x] + dinv[e.y]) + (dinv[e.z] + dinv[e.w]);
            }
        }
        float dn = dinv[n];
        float4 v;
        v.x = ax * dn; v.y = ay * dn; v.z = az * dn; v.w = aw * dn;
        if (HAS_R) {
            float4 r = R4[idx];
            v.x = fmaxf(v.x + r.x, 0.f);
            v.y = fmaxf(v.y + r.y, 0.f);
            v.z = fmaxf(v.z + r.z, 0.f);
            v.w = fmaxf(v.w + r.w, 0.f);
        }
        if (WRITE_RAW) raw4[idx] = v;
        if (WRITE_SCALED) {
            float4 s4;
            s4.x = v.x * dn; s4.y = v.y * dn; s4.z = v.z * dn; s4.w = v.w * dn;
            scaled4[idx] = s4;
        }
        if (COMPUTE_S) {
            if (q == 0) sv[n] = sd * dn;
        }
    }
}

// ---------------- layer-1 t=1 epilogue: h1p = dinv*mean_k relu(agg@w1w+R); z0 = h1.u0 ----------------
__global__ void k_post1(const float4* __restrict__ A4, const float4* __restrict__ R4,
                        const float* __restrict__ w1w, const float* __restrict__ dinv,
                        const float* __restrict__ u,
                        float4* __restrict__ h1p4, float* __restrict__ z0, int N) {
    __shared__ float4 Ws[192];  // [3][16][4] float4 of w1w[k][i][o]
    const float4* w4 = (const float4*)w1w;
    for (int i = threadIdx.x; i < 192; i += blockDim.x) Ws[i] = w4[i];
    __syncthreads();
    const int total = N * 4;
    const int stride = gridDim.x * blockDim.x;
    for (int idx = blockIdx.x * blockDim.x + threadIdx.x; idx < total; idx += stride) {
        int n = idx >> 2;
        int o4 = idx & 3;
        const float4* ap = A4 + (size_t)n * 12;
        float4 sum = make_float4(0.f, 0.f, 0.f, 0.f);
#pragma unroll
        for (int k = 0; k < 3; ++k) {
            float4 d = R4[(size_t)n * 12 + k * 4 + o4];
#pragma unroll
            for (int i4 = 0; i4 < 4; ++i4) {
                float4 av = ap[k * 4 + i4];
                float4 w0 = Ws[(k * 16 + i4 * 4 + 0) * 4 + o4];
                float4 w1 = Ws[(k * 16 + i4 * 4 + 1) * 4 + o4];
                float4 w2 = Ws[(k * 16 + i4 * 4 + 2) * 4 + o4];
                float4 w3 = Ws[(k * 16 + i4 * 4 + 3) * 4 + o4];
                d.x = fmaf(av.x, w0.x, fmaf(av.y, w1.x, fmaf(av.z, w2.x, fmaf(av.w, w3.x, d.x))));
                d.y = fmaf(av.x, w0.y, fmaf(av.y, w1.y, fmaf(av.z, w2.y, fmaf(av.w, w3.y, d.y))));
                d.z = fmaf(av.x, w0.z, fmaf(av.y, w1.z, fmaf(av.z, w2.z, fmaf(av.w, w3.z, d.z))));
                d.w = fmaf(av.x, w0.w, fmaf(av.y, w1.w, fmaf(av.z, w2.w, fmaf(av.w, w3.w, d.w))));
            }
            d.x = fmaxf(d.x, 0.f); d.y = fmaxf(d.y, 0.f);
            d.z = fmaxf(d.z, 0.f); d.w = fmaxf(d.w, 0.f);
            sum.x += d.x; sum.y += d.y; sum.z += d.z; sum.w += d.w;
        }
        const float third = 1.0f / 3.0f;
        sum.x *= third; sum.y *= third; sum.z *= third; sum.w *= third;
        float dn = dinv[n];
        float4 sp;
        sp.x = sum.x * dn; sp.y = sum.y * dn; sp.z = sum.z * dn; sp.w = sum.w * dn;
        h1p4[idx] = sp;
        float4 u0q = ((const float4*)u)[o4];
        float part = sum.x * u0q.x + sum.y * u0q.y + sum.z * u0q.z + sum.w * u0q.w;
        part += __shfl_down(part, 2, 4);
        part += __shfl_down(part, 1, 4);
        if (o4 == 0) z0[n] = part;
    }
}

// ---------------- prop16 #1: g1 = A_n h1; writes g1p (scaled) and z1 = g1.u1 ----------------
__global__ void k_prop16z(const float4* __restrict__ h1p4,
                          const int* __restrict__ rowptr, const int* __restrict__ esrc,
                          const float* __restrict__ dinv, const float* __restrict__ u,
                          float4* __restrict__ g1p4, float* __restrict__ z1, int N) {
    const int total = N * 4;
    const int stride = gridDim.x * blockDim.x;
    for (int idx = blockIdx.x * blockDim.x + threadIdx.x; idx < total; idx += stride) {
        int n = idx >> 2;
        int q = idx & 3;
        int beg = rowptr[n], end = rowptr[n + 1];
        float ax = 0.f, ay = 0.f, az = 0.f, aw = 0.f;
        for (int p = beg; p < end; p += 4) {
            int4 e = *(const int4*)(esrc + p);
            float4 v0 = h1p4[(size_t)e.x * 4 + q];
            float4 v1 = h1p4[(size_t)e.y * 4 + q];
            float4 v2 = h1p4[(size_t)e.z * 4 + q];
            float4 v3 = h1p4[(size_t)e.w * 4 + q];
            ax += (v0.x + v1.x) + (v2.x + v3.x);
            ay += (v0.y + v1.y) + (v2.y + v3.y);
            az += (v0.z + v1.z) + (v2.z + v3.z);
            aw += (v0.w + v1.w) + (v2.w + v3.w);
        }
        float dn = dinv[n];
        float4 v;
        v.x = ax * dn; v.y = ay * dn; v.z = az * dn; v.w = aw * dn;
        float4 s4;
        s4.x = v.x * dn; s4.y = v.y * dn; s4.z = v.z * dn; s4.w = v.w * dn;
        g1p4[idx] = s4;
        float4 u1q = ((const float4*)u)[4 + q];
        float part = v.x * u1q.x + v.y * u1q.y + v.z * u1q.z + v.w * u1q.w;
        part += __shfl_down(part, 2, 4);
        part += __shfl_down(part, 1, 4);
        if (q == 0) z1[n] = part;
    }
}

// ---------------- prop16 #2 fused with score/pool: g2 in-register ----------------
__global__ void k_score(const float4* __restrict__ g1p4,
                        const int* __restrict__ rowptr, const int* __restrict__ esrc,
                        const float* __restrict__ dinv, const float* __restrict__ u,
                        const float* __restrict__ z0, const float* __restrict__ z1,
                        const float* __restrict__ sv, const int* __restrict__ batch,
                        float* __restrict__ out, int N) {
    const int total = N * 4;
    const int stride = gridDim.x * blockDim.x;
    for (int idx = blockIdx.x * blockDim.x + threadIdx.x; idx < total; idx += stride) {
        int n = idx >> 2;
        int q = idx & 3;
        int beg = rowptr[n], end = rowptr[n + 1];
        float ax = 0.f, ay = 0.f, az = 0.f, aw = 0.f;
        for (int p = beg; p < end; p += 4) {
            int4 e = *(const int4*)(esrc + p);
            float4 v0 = g1p4[(size_t)e.x * 4 + q];
            float4 v1 = g1p4[(size_t)e.y * 4 + q];
            float4 v2 = g1p4[(size_t)e.z * 4 + q];
            float4 v3 = g1p4[(size_t)e.w * 4 + q];
            ax += (v0.x + v1.x) + (v2.x + v3.x);
            ay += (v0.y + v1.y) + (v2.y + v3.y);
            az += (v0.z + v1.z) + (v2.z + v3.z);
            aw += (v0.w + v1.w) + (v2.w + v3.w);
        }
        float dn = dinv[n];
        float4 u2q = ((const float4*)u)[8 + q];
        float part = (ax * dn) * u2q.x + (ay * dn) * u2q.y +
                     (az * dn) * u2q.z + (aw * dn) * u2q.w;
        part += __shfl_down(part, 2, 4);
        part += __shfl_down(part, 1, 4);
        if (q == 0) {
            float v = part + z0[n] + z1[n] + sv[n] * u[48] + u[49];
            atomicAdd(&out[batch[n]], v);
        }
    }
}

// ---------------- precombine layer-2+head weights; blocks 1..8 init out ----------------
__global__ void k_comb(const float* __restrict__ w2i, const float* __restrict__ w2w,
                       const float* __restrict__ w2r, const float* __restrict__ b2,
                       const float* __restrict__ wg, const float* __restrict__ bg,
                       float* __restrict__ u, float* __restrict__ out) {
    if (blockIdx.x > 0) {
        int g = (blockIdx.x - 1) * 256 + threadIdx.x;
        if (g < NG) out[g] = bg[0];
        return;
    }
    __shared__ float t[3][64];
    int tid = threadIdx.x;
    if (tid < 64) {
#pragma unroll
        for (int k = 0; k < 3; ++k) {
            float a = 0.f;
            for (int j = 0; j < 64; ++j) a = fmaf(w2w[k * 4096 + tid * 64 + j], wg[j], a);
            t[k][tid] = a;
        }
    }
    __syncthreads();
    if (tid < 64) {
        float wgv = wg[tid];
        float tk0 = t[0][tid], tk1 = t[1][tid], tk2 = t[2][tid];
        const float third = 1.0f / 3.0f;
        for (int j = 0; j < 16; ++j) {
            float wi0 = w2i[j * 64 + tid], wi1 = w2i[1024 + j * 64 + tid], wi2 = w2i[2048 + j * 64 + tid];
            float wr0 = w2r[j * 64 + tid], wr1 = w2r[1024 + j * 64 + tid], wr2 = w2r[2048 + j * 64 + tid];
            float a2 = wi0 * tk0 + wi1 * tk1 + wi2 * tk2;
            float a1 = wr0 * tk0 + wr1 * tk1 + wr2 * tk2;
            float a0 = (wr0 + wr1 + wr2) * wgv;
#pragma unroll
            for (int off = 32; off > 0; off >>= 1) {
                a2 += __shfl_down(a2, off, 64);
                a1 += __shfl_down(a1, off, 64);
                a0 += __shfl_down(a0, off, 64);
            }
            if (tid == 0) {
                u[j] = a0 * third;
                u[16 + j] = a1 * third;
                u[32 + j] = a2 * third;
            }
        }
        float b0 = b2[tid], b1v = b2[64 + tid], b2v = b2[128 + tid];
        float c0 = b0 * tk0 + b1v * tk1 + b2v * tk2;
        float c1 = (b0 + b1v + b2v) * wgv;
#pragma unroll
        for (int off = 32; off > 0; off >>= 1) {
            c0 += __shfl_down(c0, off, 64);
            c1 += __shfl_down(c1, off, 64);
        }
        if (tid == 0) {
            u[48] = c0 * third;
            u[49] = c1 * third;
        }
    }
}

extern "C" void kernel_launch(void* const* d_in, const int* in_sizes, int n_in,
                              void* d_out, int out_size, void* d_ws, size_t ws_size,
                              hipStream_t stream) {
    const float* x   = (const float*)d_in[0];
    const int*   ei  = (const int*)d_in[1];
    const int*   row = ei;
    const int*   col = ei + NE;
    const int*   batch = (const int*)d_in[2];
    const float* w1i = (const float*)d_in[3];
    const float* w1w = (const float*)d_in[4];
    const float* w1r = (const float*)d_in[5];
    const float* w1b = (const float*)d_in[6];
    const float* w2i = (const float*)d_in[7];
    const float* w2w = (const float*)d_in[8];
    const float* w2r = (const float*)d_in[9];
    const float* w2b = (const float*)d_in[10];
    const float* wg  = (const float*)d_in[11];
    const float* bg  = (const float*)d_in[12];
    float* out = (float*)d_out;

    // workspace layout (every segment 16B-aligned)
    float* A    = (float*)d_ws;                      // [N+1, 48]
    float* B    = A + (size_t)(NN + 1) * 48;         // [N+1, 48]
    float* R    = B + (size_t)(NN + 1) * 48;         // [N, 48]
    float* h1p  = R + (size_t)NN * 48;               // [N+1, 16]
    float* g1p  = h1p + (size_t)(NN + 1) * 16;       // [N+1, 16]
    float* dinv = g1p + (size_t)(NN + 1) * 16;       // [N+1] (pad to 100004)
    float* sv   = dinv + 100004;                     // [N]
    float* z0   = sv + NN;                           // [N]
    float* z1   = z0 + NN;                           // [N]
    float* u    = z1 + NN;                           // [64]
    int*   cnt  = (int*)(u + 64);                    // [N]
    int*   excl = cnt + NN;                          // [N]
    int*   rowptr = excl + NN;                       // [N+1] (pad to 100004)
    int*   btot = rowptr + 100004;                   // [512] packed
    int*   boff = btot + 512;                        // [512]
    int*   qoff = boff + 512;                        // [512]
    int*   bcur = qoff + 512;                        // [512]
    int*   pairs = bcur + 512;                       // [NE]
    int*   esrc = pairs + NE;                        // [ESZ]

    const int T = 256;

    // ---- init + CSR build (bucketed, low write-amplification) ----
    k_init<<<1024, T, 0, stream>>>(cnt, (float4*)A, (float4*)B,
                                   (float4*)h1p, (float4*)g1p);
    k_hist<<<cdiv(NE, T), T, 0, stream>>>(col, cnt, NE);
    k_scan1<<<NBK, 256, 0, stream>>>(cnt, dinv, excl, btot, NN);
    k_scan2<<<1, 512, 0, stream>>>(btot, boff, qoff, NBK);
    k_scan3<<<cdiv(NN, T), T, 0, stream>>>(excl, boff, qoff, rowptr, bcur, dinv, NN);
    k_part<<<128, T, 0, stream>>>(row, col, bcur, pairs, NE);
    k_bucket<<<NBK, T, 0, stream>>>(pairs, qoff, boff, excl, rowptr, esrc, NN);

    // ---- precombined layer-2+head weights + out init ----
    k_comb<<<9, T, 0, stream>>>(w2i, w2w, w2r, w2b, wg, bg, u, out);

    // ---- layer 1 input transforms ----
    k_mm<75, 3, 16, 0, 1><<<2048, T, 0, stream>>>(x, w1i, nullptr, dinv, (float4*)A, NN);
    k_mm<75, 3, 16, 1, 0><<<2048, T, 0, stream>>>(x, w1r, w1b, nullptr, (float4*)R, NN);

    // t=0: B = dinv * relu(prop(A) + R); also sv[n]
    k_prop48<1, 1, 0, 1><<<cdiv((long long)NN * 12, T), T, 0, stream>>>(
        (const float4*)A, (const float4*)R, rowptr, esrc, dinv, sv,
        nullptr, (float4*)B, NN);
    // t=1 agg: A = dinv * prop(B)
    k_prop48<0, 0, 1, 0><<<cdiv((long long)NN * 12, T), T, 0, stream>>>(
        (const float4*)B, nullptr, rowptr, esrc, dinv, nullptr,
        (float4*)A, nullptr, NN);
    // h1p = dinv*mean_k relu(A@w1w + R); z0 = h1.u0
    k_post1<<<cdiv((long long)NN * 4, T), T, 0, stream>>>(
        (const float4*)A, (const float4*)R, w1w, dinv, u, (float4*)h1p, z0, NN);

    // ---- layer 2 (linearized): g1p + z1, then fused g2+score+pool ----
    k_prop16z<<<cdiv((long long)NN * 4, T), T, 0, stream>>>(
        (const float4*)h1p, rowptr, esrc, dinv, u, (float4*)g1p, z1, NN);
    k_score<<<cdiv((long long)NN * 4, T), T, 0, stream>>>(
        (const float4*)g1p, rowptr, esrc, dinv, u, z0, z1, sv, batch, out, NN);
}

// Round 8
// 259.349 us; speedup vs baseline: 5.8642x; 1.2395x over previous
//
#include <hip/hip_runtime.h>

#define NN 100000
#define NE 1200000
#define NG 2048
#define NBK 391           // cdiv(NN,256) buckets of 256 nodes
#define CAPQ 4096         // raw records capacity per bucket (mean 3070, >18 sigma)
#define CAPE 5120         // padded CSR capacity per bucket (raw + <=768 pad)

static inline int cdiv(long long a, int b) { return (int)((a + b - 1) / b); }

// ---------------- init: bucket cursors + sentinel rows ----------------
__global__ void k_init(int* __restrict__ gcur, float4* __restrict__ A4,
                       float4* __restrict__ B4, float4* __restrict__ h1p4,
                       float4* __restrict__ g1p4, float* __restrict__ dinv) {
    int g = blockIdx.x * blockDim.x + threadIdx.x;
    if (g < NBK) gcur[g] = g * CAPQ;
    if (g == NBK) dinv[NN] = 0.f;
    float4 z = make_float4(0.f, 0.f, 0.f, 0.f);
    int s = g - 512;
    if (s >= 0 && s < 12) {
        A4[(size_t)NN * 12 + s] = z;
        B4[(size_t)NN * 12 + s] = z;
    } else if (s >= 12 && s < 16) {
        h1p4[(size_t)NN * 4 + (s - 12)] = z;
        g1p4[(size_t)NN * 4 + (s - 12)] = z;
    }
}

// ---------------- phase 1: partition edges bucket-major into pairs ----------------
__global__ __launch_bounds__(256) void k_part(const int* __restrict__ row,
                                              const int* __restrict__ col,
                                              int* __restrict__ gcur,
                                              int* __restrict__ pairs, int E) {
    __shared__ int hcnt[NBK];
    __shared__ int hbase[NBK];
    int chunk = (E + gridDim.x - 1) / gridDim.x;
    int beg = blockIdx.x * chunk;
    int end = min(E, beg + chunk);
    for (int j = threadIdx.x; j < NBK; j += 256) hcnt[j] = 0;
    __syncthreads();
    for (int e = beg + threadIdx.x; e < end; e += 256)
        atomicAdd(&hcnt[col[e] >> 8], 1);
    __syncthreads();
    for (int j = threadIdx.x; j < NBK; j += 256) {
        int c = hcnt[j];
        hbase[j] = c > 0 ? atomicAdd(&gcur[j], c) : 0;
        hcnt[j] = 0;
    }
    __syncthreads();
    for (int e = beg + threadIdx.x; e < end; e += 256) {
        int cc = col[e];
        int b = cc >> 8;
        int r = atomicAdd(&hcnt[b], 1);
        int pos = hbase[b] + r;
        if (pos < (b + 1) * CAPQ) pairs[pos] = ((cc & 255) << 17) | row[e];
    }
}

// ---------------- phase 2: per-bucket count/scan/dinv/rowptr + staged scatter ----------------
// packed rowptr: bits[0:20) = beg>>2, bits[20:31) = paddedCount>>2
__global__ __launch_bounds__(256) void k_bucket(const int* __restrict__ pairs,
                                                const int* __restrict__ gcur,
                                                int* __restrict__ esrc,
                                                int* __restrict__ rowptrp,
                                                float* __restrict__ dinv, int N) {
    __shared__ int stage[CAPE];
    __shared__ int lcnt[256];
    __shared__ int s[256];
    __shared__ int tot;
    int b = blockIdx.x;
    int base = b << 8;
    int nn = min(256, N - base);
    int qb = b * CAPQ;
    int qe = min(gcur[b], qb + CAPQ);
    int tid = threadIdx.x;
    lcnt[tid] = 0;
    __syncthreads();
    for (int p = qb + tid; p < qe; p += 256)
        atomicAdd(&lcnt[pairs[p] >> 17], 1);
    __syncthreads();
    int c = lcnt[tid];
    int pc = (c + 3) & ~3;
    s[tid] = pc;
    __syncthreads();
    for (int off = 1; off < 256; off <<= 1) {
        int t = (tid >= off) ? s[tid - off] : 0;
        __syncthreads();
        s[tid] += t;
        __syncthreads();
    }
    int myofs = s[tid] - pc;   // exclusive padded offset within bucket
    if (tid == 255) tot = s[255];
    __syncthreads();
    int padded = tot;
    if (tid < nn) {
        dinv[base + tid] = c > 0 ? rsqrtf((float)c) : 0.f;
        rowptrp[base + tid] = ((b * CAPE + myofs) >> 2) | ((pc >> 2) << 20);
    }
    for (int i = tid; i < padded; i += 256) stage[i] = N;  // sentinel
    lcnt[tid] = myofs;   // reuse as cursor
    __syncthreads();
    for (int p = qb + tid; p < qe; p += 256) {
        int v = pairs[p];
        int cl = v >> 17, r = v & 0x1FFFF;
        int pos = atomicAdd(&lcnt[cl], 1);
        stage[pos] = r;
    }
    __syncthreads();
    int segbase = b * CAPE;
    for (int i = tid; i < padded; i += 256) esrc[segbase + i] = stage[i];
}

// ---------------- fused layer-1 input transforms: A=(x@w1i)*dinv, R=x@w1r+b ----------------
// uniform control flow: every thread computes BOTH quads, both stores unconditional
__global__ void k_mmAR(const float* __restrict__ x,
                       const float* __restrict__ w1i, const float* __restrict__ w1r,
                       const float* __restrict__ b1, const float* __restrict__ dinv,
                       float4* __restrict__ A4, float4* __restrict__ R4, int N) {
    __shared__ float4 Wi[900];   // [3][75][4] float4
    __shared__ float4 Wr[900];
    __shared__ float4 Bs[12];
    const float4* wi4 = (const float4*)w1i;
    const float4* wr4 = (const float4*)w1r;
    for (int i = threadIdx.x; i < 900; i += blockDim.x) { Wi[i] = wi4[i]; Wr[i] = wr4[i]; }
    if (threadIdx.x < 12) Bs[threadIdx.x] = ((const float4*)b1)[threadIdx.x];
    __syncthreads();
    const int total = N * 12;
    const int stride = gridDim.x * blockDim.x;
    for (int idx = blockIdx.x * blockDim.x + threadIdx.x; idx < total; idx += stride) {
        int n = idx / 12;
        int q = idx - n * 12;
        int k = q >> 2, o4 = q & 3;
        const float* xp = x + (size_t)n * 75;
        const float4* wpi = Wi + (k * 75) * 4 + o4;
        const float4* wpr = Wr + (k * 75) * 4 + o4;
        float aix = 0.f, aiy = 0.f, aiz = 0.f, aiw = 0.f;
        float4 br = Bs[q];
        float arx = br.x, ary = br.y, arz = br.z, arw = br.w;
#pragma unroll
        for (int f = 0; f < 75; ++f) {
            float xv = xp[f];
            float4 wi = wpi[f * 4];
            float4 wr = wpr[f * 4];
            aix = fmaf(xv, wi.x, aix);
            aiy = fmaf(xv, wi.y, aiy);
            aiz = fmaf(xv, wi.z, aiz);
            aiw = fmaf(xv, wi.w, aiw);
            arx = fmaf(xv, wr.x, arx);
            ary = fmaf(xv, wr.y, ary);
            arz = fmaf(xv, wr.z, arz);
            arw = fmaf(xv, wr.w, arw);
        }
        float dn = dinv[n];
        A4[idx] = make_float4(aix * dn, aiy * dn, aiz * dn, aiw * dn);
        R4[idx] = make_float4(arx, ary, arz, arw);
    }
}

// ---------------- 48-wide CSR prop (packed rowptr, int4 esrc) ----------------
template <int HAS_R, int COMPUTE_S, int WRITE_RAW, int WRITE_SCALED>
__global__ void k_prop48(const float4* __restrict__ src4, const float4* __restrict__ R4,
                         const int* __restrict__ rowptrp, const int* __restrict__ esrc,
                         const float* __restrict__ dinv, float* __restrict__ sv,
                         float4* __restrict__ raw4, float4* __restrict__ scaled4, int N) {
    const int total = N * 12;
    const int stride = gridDim.x * blockDim.x;
    for (int idx = blockIdx.x * blockDim.x + threadIdx.x; idx < total; idx += stride) {
        int n = idx / 12;
        int q = idx - n * 12;
        int rp = rowptrp[n];
        int beg = (rp & 0xFFFFF) << 2;
        int end = beg + ((rp >> 20) << 2);
        float ax = 0.f, ay = 0.f, az = 0.f, aw = 0.f;
        float sd = 0.f;
        for (int p = beg; p < end; p += 4) {
            int4 e = *(const int4*)(esrc + p);
            float4 v0 = src4[(size_t)e.x * 12 + q];
            float4 v1 = src4[(size_t)e.y * 12 + q];
            float4 v2 = src4[(size_t)e.z * 12 + q];
            float4 v3 = src4[(size_t)e.w * 12 + q];
            ax += (v0.x + v1.x) + (v2.x + v3.x);
            ay += (v0.y + v1.y) + (v2.y + v3.y);
            az += (v0.z + v1.z) + (v2.z + v3.z);
            aw += (v0.w + v1.w) + (v2.w + v3.w);
            if (COMPUTE_S) {
                if (q == 0)
                    sd += (dinv[e.x] + dinv[e.y]) + (dinv[e.z] + dinv[e.w]);
            }
        }
        float dn = dinv[n];
        float4 v;
        v.x = ax * dn; v.y = ay * dn; v.z = az * dn; v.w = aw * dn;
        if (HAS_R) {
            float4 r = R4[idx];
            v.x = fmaxf(v.x + r.x, 0.f);
            v.y = fmaxf(v.y + r.y, 0.f);
            v.z = fmaxf(v.z + r.z, 0.f);
            v.w = fmaxf(v.w + r.w, 0.f);
        }
        if (WRITE_RAW) raw4[idx] = v;
        if (WRITE_SCALED) {
            float4 s4;
            s4.x = v.x * dn; s4.y = v.y * dn; s4.z = v.z * dn; s4.w = v.w * dn;
            scaled4[idx] = s4;
        }
        if (COMPUTE_S) {
            if (q == 0) sv[n] = sd * dn;
        }
    }
}

// ---------------- layer-1 t=1 epilogue: h1p = dinv*mean_k relu(agg@w1w+R); z0 = h1.u0 ----------------
__global__ void k_post1(const float4* __restrict__ A4, const float4* __restrict__ R4,
                        const float* __restrict__ w1w, const float* __restrict__ dinv,
                        const float* __restrict__ u,
                        float4* __restrict__ h1p4, float* __restrict__ z0, int N) {
    __shared__ float4 Ws[192];  // [3][16][4] float4 of w1w[k][i][o]
    const float4* w4 = (const float4*)w1w;
    for (int i = threadIdx.x; i < 192; i += blockDim.x) Ws[i] = w4[i];
    __syncthreads();
    const int total = N * 4;
    const int stride = gridDim.x * blockDim.x;
    for (int idx = blockIdx.x * blockDim.x + threadIdx.x; idx < total; idx += stride) {
        int n = idx >> 2;
        int o4 = idx & 3;
        const float4* ap = A4 + (size_t)n * 12;
        float4 sum = make_float4(0.f, 0.f, 0.f, 0.f);
#pragma unroll
        for (int k = 0; k < 3; ++k) {
            float4 d = R4[(size_t)n * 12 + k * 4 + o4];
#pragma unroll
            for (int i4 = 0; i4 < 4; ++i4) {
                float4 av = ap[k * 4 + i4];
                float4 w0 = Ws[(k * 16 + i4 * 4 + 0) * 4 + o4];
                float4 w1 = Ws[(k * 16 + i4 * 4 + 1) * 4 + o4];
                float4 w2 = Ws[(k * 16 + i4 * 4 + 2) * 4 + o4];
                float4 w3 = Ws[(k * 16 + i4 * 4 + 3) * 4 + o4];
                d.x = fmaf(av.x, w0.x, fmaf(av.y, w1.x, fmaf(av.z, w2.x, fmaf(av.w, w3.x, d.x))));
                d.y = fmaf(av.x, w0.y, fmaf(av.y, w1.y, fmaf(av.z, w2.y, fmaf(av.w, w3.y, d.y))));
                d.z = fmaf(av.x, w0.z, fmaf(av.y, w1.z, fmaf(av.z, w2.z, fmaf(av.w, w3.z, d.z))));
                d.w = fmaf(av.x, w0.w, fmaf(av.y, w1.w, fmaf(av.z, w2.w, fmaf(av.w, w3.w, d.w))));
            }
            d.x = fmaxf(d.x, 0.f); d.y = fmaxf(d.y, 0.f);
            d.z = fmaxf(d.z, 0.f); d.w = fmaxf(d.w, 0.f);
            sum.x += d.x; sum.y += d.y; sum.z += d.z; sum.w += d.w;
        }
        const float third = 1.0f / 3.0f;
        sum.x *= third; sum.y *= third; sum.z *= third; sum.w *= third;
        float dn = dinv[n];
        float4 sp;
        sp.x = sum.x * dn; sp.y = sum.y * dn; sp.z = sum.z * dn; sp.w = sum.w * dn;
        h1p4[idx] = sp;
        float4 u0q = ((const float4*)u)[o4];
        float part = sum.x * u0q.x + sum.y * u0q.y + sum.z * u0q.z + sum.w * u0q.w;
        part += __shfl_down(part, 2, 4);
        part += __shfl_down(part, 1, 4);
        if (o4 == 0) z0[n] = part;
    }
}

// ---------------- prop16 #1: g1 = A_n h1; writes g1p (scaled) and z1 = g1.u1 ----------------
__global__ void k_prop16z(const float4* __restrict__ h1p4,
                          const int* __restrict__ rowptrp, const int* __restrict__ esrc,
                          const float* __restrict__ dinv, const float* __restrict__ u,
                          float4* __restrict__ g1p4, float* __restrict__ z1, int N) {
    const int total = N * 4;
    const int stride = gridDim.x * blockDim.x;
    for (int idx = blockIdx.x * blockDim.x + threadIdx.x; idx < total; idx += stride) {
        int n = idx >> 2;
        int q = idx & 3;
        int rp = rowptrp[n];
        int beg = (rp & 0xFFFFF) << 2;
        int end = beg + ((rp >> 20) << 2);
        float ax = 0.f, ay = 0.f, az = 0.f, aw = 0.f;
        for (int p = beg; p < end; p += 4) {
            int4 e = *(const int4*)(esrc + p);
            float4 v0 = h1p4[(size_t)e.x * 4 + q];
            float4 v1 = h1p4[(size_t)e.y * 4 + q];
            float4 v2 = h1p4[(size_t)e.z * 4 + q];
            float4 v3 = h1p4[(size_t)e.w * 4 + q];
            ax += (v0.x + v1.x) + (v2.x + v3.x);
            ay += (v0.y + v1.y) + (v2.y + v3.y);
            az += (v0.z + v1.z) + (v2.z + v3.z);
            aw += (v0.w + v1.w) + (v2.w + v3.w);
        }
        float dn = dinv[n];
        float4 v;
        v.x = ax * dn; v.y = ay * dn; v.z = az * dn; v.w = aw * dn;
        float4 s4;
        s4.x = v.x * dn; s4.y = v.y * dn; s4.z = v.z * dn; s4.w = v.w * dn;
        g1p4[idx] = s4;
        float4 u1q = ((const float4*)u)[4 + q];
        float part = v.x * u1q.x + v.y * u1q.y + v.z * u1q.z + v.w * u1q.w;
        part += __shfl_down(part, 2, 4);
        part += __shfl_down(part, 1, 4);
        if (q == 0) z1[n] = part;
    }
}

// ---------------- prop16 #2 fused with score/pool: g2 in-register ----------------
__global__ void k_score(const float4* __restrict__ g1p4,
                        const int* __restrict__ rowptrp, const int* __restrict__ esrc,
                        const float* __restrict__ dinv, const float* __restrict__ u,
                        const float* __restrict__ z0, const float* __restrict__ z1,
                        const float* __restrict__ sv, const int* __restrict__ batch,
                        float* __restrict__ out, int N) {
    const int total = N * 4;
    const int stride = gridDim.x * blockDim.x;
    for (int idx = blockIdx.x * blockDim.x + threadIdx.x; idx < total; idx += stride) {
        int n = idx >> 2;
        int q = idx & 3;
        int rp = rowptrp[n];
        int beg = (rp & 0xFFFFF) << 2;
        int end = beg + ((rp >> 20) << 2);
        float ax = 0.f, ay = 0.f, az = 0.f, aw = 0.f;
        for (int p = beg; p < end; p += 4) {
            int4 e = *(const int4*)(esrc + p);
            float4 v0 = g1p4[(size_t)e.x * 4 + q];
            float4 v1 = g1p4[(size_t)e.y * 4 + q];
            float4 v2 = g1p4[(size_t)e.z * 4 + q];
            float4 v3 = g1p4[(size_t)e.w * 4 + q];
            ax += (v0.x + v1.x) + (v2.x + v3.x);
            ay += (v0.y + v1.y) + (v2.y + v3.y);
            az += (v0.z + v1.z) + (v2.z + v3.z);
            aw += (v0.w + v1.w) + (v2.w + v3.w);
        }
        float dn = dinv[n];
        float4 u2q = ((const float4*)u)[8 + q];
        float part = (ax * dn) * u2q.x + (ay * dn) * u2q.y +
                     (az * dn) * u2q.z + (aw * dn) * u2q.w;
        part += __shfl_down(part, 2, 4);
        part += __shfl_down(part, 1, 4);
        if (q == 0) {
            float v = part + z0[n] + z1[n] + sv[n] * u[48] + u[49];
            atomicAdd(&out[batch[n]], v);
        }
    }
}

// ---------------- precombine layer-2+head weights; blocks 1..8 init out ----------------
__global__ void k_comb(const float* __restrict__ w2i, const float* __restrict__ w2w,
                       const float* __restrict__ w2r, const float* __restrict__ b2,
                       const float* __restrict__ wg, const float* __restrict__ bg,
                       float* __restrict__ u, float* __restrict__ out) {
    if (blockIdx.x > 0) {
        int g = (blockIdx.x - 1) * 256 + threadIdx.x;
        if (g < NG) out[g] = bg[0];
        return;
    }
    __shared__ float t[3][64];
    int tid = threadIdx.x;
    if (tid < 64) {
#pragma unroll
        for (int k = 0; k < 3; ++k) {
            float a = 0.f;
            for (int j = 0; j < 64; ++j) a = fmaf(w2w[k * 4096 + tid * 64 + j], wg[j], a);
            t[k][tid] = a;
        }
    }
    __syncthreads();
    if (tid < 64) {
        float wgv = wg[tid];
        float tk0 = t[0][tid], tk1 = t[1][tid], tk2 = t[2][tid];
        const float third = 1.0f / 3.0f;
        for (int j = 0; j < 16; ++j) {
            float wi0 = w2i[j * 64 + tid], wi1 = w2i[1024 + j * 64 + tid], wi2 = w2i[2048 + j * 64 + tid];
            float wr0 = w2r[j * 64 + tid], wr1 = w2r[1024 + j * 64 + tid], wr2 = w2r[2048 + j * 64 + tid];
            float a2 = wi0 * tk0 + wi1 * tk1 + wi2 * tk2;
            float a1 = wr0 * tk0 + wr1 * tk1 + wr2 * tk2;
            float a0 = (wr0 + wr1 + wr2) * wgv;
#pragma unroll
            for (int off = 32; off > 0; off >>= 1) {
                a2 += __shfl_down(a2, off, 64);
                a1 += __shfl_down(a1, off, 64);
                a0 += __shfl_down(a0, off, 64);
            }
            if (tid == 0) {
                u[j] = a0 * third;
                u[16 + j] = a1 * third;
                u[32 + j] = a2 * third;
            }
        }
        float b0 = b2[tid], b1v = b2[64 + tid], b2v = b2[128 + tid];
        float c0 = b0 * tk0 + b1v * tk1 + b2v * tk2;
        float c1 = (b0 + b1v + b2v) * wgv;
#pragma unroll
        for (int off = 32; off > 0; off >>= 1) {
            c0 += __shfl_down(c0, off, 64);
            c1 += __shfl_down(c1, off, 64);
        }
        if (tid == 0) {
            u[48] = c0 * third;
            u[49] = c1 * third;
        }
    }
}

extern "C" void kernel_launch(void* const* d_in, const int* in_sizes, int n_in,
                              void* d_out, int out_size, void* d_ws, size_t ws_size,
                              hipStream_t stream) {
    const float* x   = (const float*)d_in[0];
    const int*   ei  = (const int*)d_in[1];
    const int*   row = ei;
    const int*   col = ei + NE;
    const int*   batch = (const int*)d_in[2];
    const float* w1i = (const float*)d_in[3];
    const float* w1w = (const float*)d_in[4];
    const float* w1r = (const float*)d_in[5];
    const float* w1b = (const float*)d_in[6];
    const float* w2i = (const float*)d_in[7];
    const float* w2w = (const float*)d_in[8];
    const float* w2r = (const float*)d_in[9];
    const float* w2b = (const float*)d_in[10];
    const float* wg  = (const float*)d_in[11];
    const float* bg  = (const float*)d_in[12];
    float* out = (float*)d_out;

    // workspace layout (every segment 16B-aligned)
    float* A    = (float*)d_ws;                      // [N+1, 48]
    float* B    = A + (size_t)(NN + 1) * 48;         // [N+1, 48]
    float* R    = B + (size_t)(NN + 1) * 48;         // [N, 48]
    float* h1p  = R + (size_t)NN * 48;               // [N+1, 16]
    float* g1p  = h1p + (size_t)(NN + 1) * 16;       // [N+1, 16]
    float* dinv = g1p + (size_t)(NN + 1) * 16;       // [N+1] (pad to 100004)
    float* sv   = dinv + 100004;                     // [N]
    float* z0   = sv + NN;                           // [N]
    float* z1   = z0 + NN;                           // [N]
    float* u    = z1 + NN;                           // [64]
    int*   rowptrp = (int*)(u + 64);                 // [N] packed
    int*   gcur = rowptrp + NN;                      // [512]
    int*   pairs = gcur + 512;                       // [(NBK+1)*CAPQ]
    int*   esrc = pairs + (size_t)(NBK + 1) * CAPQ;  // [NBK*CAPE]

    const int T = 256;

    // ---- CSR build (histogram-free, bucketed) ----
    k_init<<<3, T, 0, stream>>>(gcur, (float4*)A, (float4*)B,
                                (float4*)h1p, (float4*)g1p, dinv);
    k_part<<<128, T, 0, stream>>>(row, col, gcur, pairs, NE);
    k_bucket<<<NBK, T, 0, stream>>>(pairs, gcur, esrc, rowptrp, dinv, NN);

    // ---- precombined layer-2+head weights + out init ----
    k_comb<<<9, T, 0, stream>>>(w2i, w2w, w2r, w2b, wg, bg, u, out);

    // ---- layer 1 input transforms (fused, uniform control flow) ----
    k_mmAR<<<2048, T, 0, stream>>>(x, w1i, w1r, w1b, dinv, (float4*)A, (float4*)R, NN);

    // t=0: B = dinv * relu(prop(A) + R); also sv[n]
    k_prop48<1, 1, 0, 1><<<cdiv((long long)NN * 12, T), T, 0, stream>>>(
        (const float4*)A, (const float4*)R, rowptrp, esrc, dinv, sv,
        nullptr, (float4*)B, NN);
    // t=1 agg: A = dinv * prop(B)
    k_prop48<0, 0, 1, 0><<<cdiv((long long)NN * 12, T), T, 0, stream>>>(
        (const float4*)B, nullptr, rowptrp, esrc, dinv, nullptr,
        (float4*)A, nullptr, NN);
    // h1p = dinv*mean_k relu(A@w1w + R); z0 = h1.u0
    k_post1<<<cdiv((long long)NN * 4, T), T, 0, stream>>>(
        (const float4*)A, (const float4*)R, w1w, dinv, u, (float4*)h1p, z0, NN);

    // ---- layer 2 (linearized): g1p + z1, then fused g2+score+pool ----
    k_prop16z<<<cdiv((long long)NN * 4, T), T, 0, stream>>>(
        (const float4*)h1p, rowptrp, esrc, dinv, u, (float4*)g1p, z1, NN);
    k_score<<<cdiv((long long)NN * 4, T), T, 0, stream>>>(
        (const float4*)g1p, rowptrp, esrc, dinv, u, z0, z1, sv, batch, out, NN);
}

// Round 9
// 222.025 us; speedup vs baseline: 6.8500x; 1.1681x over previous
//
#include <hip/hip_runtime.h>

#define NN 100000
#define NE 1200000
#define NG 2048
#define NBK 391           // cdiv(NN,256) buckets of 256 nodes
#define CAPQ 4096         // raw records capacity per bucket (mean 3070, >18 sigma)
#define CAPE 5120         // padded CSR capacity per bucket

static inline int cdiv(long long a, int b) { return (int)((a + b - 1) / b); }

// ---------------- bf16 helpers (RNE pack, shift unpack) ----------------
__device__ __forceinline__ unsigned short f2bf(float f) {
    unsigned int u = __float_as_uint(f);
    u += 0x7fffu + ((u >> 16) & 1u);
    return (unsigned short)(u >> 16);
}
__device__ __forceinline__ unsigned int pack2(float a, float b) {
    return (unsigned int)f2bf(a) | ((unsigned int)f2bf(b) << 16);
}
__device__ __forceinline__ float lo2f(unsigned int w) { return __uint_as_float(w << 16); }
__device__ __forceinline__ float hi2f(unsigned int w) { return __uint_as_float(w & 0xffff0000u); }

// ---------------- init: bucket cursors + sentinel rows ----------------
__global__ void k_init(int* __restrict__ gcur, uint4* __restrict__ A16,
                       uint4* __restrict__ B16, uint4* __restrict__ h1p16,
                       uint4* __restrict__ g1p16, float* __restrict__ dinv) {
    int g = blockIdx.x * blockDim.x + threadIdx.x;
    if (g < NBK) gcur[g] = g * CAPQ;
    if (g == NBK) dinv[NN] = 0.f;
    uint4 z = make_uint4(0u, 0u, 0u, 0u);
    int s = g - 512;
    if (s >= 0 && s < 6) {
        A16[(size_t)NN * 6 + s] = z;
        B16[(size_t)NN * 6 + s] = z;
    } else if (s >= 6 && s < 8) {
        h1p16[(size_t)NN * 2 + (s - 6)] = z;
        g1p16[(size_t)NN * 2 + (s - 6)] = z;
    }
}

// ---------------- phase 1: partition edges bucket-major into pairs ----------------
__global__ __launch_bounds__(256) void k_part(const int* __restrict__ row,
                                              const int* __restrict__ col,
                                              int* __restrict__ gcur,
                                              int* __restrict__ pairs, int E) {
    __shared__ int hcnt[NBK];
    __shared__ int hbase[NBK];
    int chunk = (E + gridDim.x - 1) / gridDim.x;
    int beg = blockIdx.x * chunk;
    int end = min(E, beg + chunk);
    for (int j = threadIdx.x; j < NBK; j += 256) hcnt[j] = 0;
    __syncthreads();
    for (int e = beg + threadIdx.x; e < end; e += 256)
        atomicAdd(&hcnt[col[e] >> 8], 1);
    __syncthreads();
    for (int j = threadIdx.x; j < NBK; j += 256) {
        int c = hcnt[j];
        hbase[j] = c > 0 ? atomicAdd(&gcur[j], c) : 0;
        hcnt[j] = 0;
    }
    __syncthreads();
    for (int e = beg + threadIdx.x; e < end; e += 256) {
        int cc = col[e];
        int b = cc >> 8;
        int r = atomicAdd(&hcnt[b], 1);
        int pos = hbase[b] + r;
        if (pos < (b + 1) * CAPQ) pairs[pos] = ((cc & 255) << 17) | row[e];
    }
}

// ---------------- phase 2: per-bucket count/scan/dinv/rowptr + staged scatter ----------------
// packed rowptr: bits[0:20) = beg>>2, bits[20:31) = paddedCount>>2
__global__ __launch_bounds__(256) void k_bucket(const int* __restrict__ pairs,
                                                const int* __restrict__ gcur,
                                                int* __restrict__ esrc,
                                                int* __restrict__ rowptrp,
                                                float* __restrict__ dinv, int N) {
    __shared__ int stage[CAPE];
    __shared__ int lcnt[256];
    __shared__ int s[256];
    __shared__ int tot;
    int b = blockIdx.x;
    int base = b << 8;
    int nn = min(256, N - base);
    int qb = b * CAPQ;
    int qe = min(gcur[b], qb + CAPQ);
    int tid = threadIdx.x;
    lcnt[tid] = 0;
    __syncthreads();
    for (int p = qb + tid; p < qe; p += 256)
        atomicAdd(&lcnt[pairs[p] >> 17], 1);
    __syncthreads();
    int c = lcnt[tid];
    int pc = (c + 3) & ~3;
    s[tid] = pc;
    __syncthreads();
    for (int off = 1; off < 256; off <<= 1) {
        int t = (tid >= off) ? s[tid - off] : 0;
        __syncthreads();
        s[tid] += t;
        __syncthreads();
    }
    int myofs = s[tid] - pc;
    if (tid == 255) tot = s[255];
    __syncthreads();
    int padded = tot;
    if (tid < nn) {
        dinv[base + tid] = c > 0 ? rsqrtf((float)c) : 0.f;
        rowptrp[base + tid] = ((b * CAPE + myofs) >> 2) | ((pc >> 2) << 20);
    }
    for (int i = tid; i < padded; i += 256) stage[i] = N;  // sentinel
    lcnt[tid] = myofs;
    __syncthreads();
    for (int p = qb + tid; p < qe; p += 256) {
        int v = pairs[p];
        int cl = v >> 17, r = v & 0x1FFFF;
        int pos = atomicAdd(&lcnt[cl], 1);
        stage[pos] = r;
    }
    __syncthreads();
    int segbase = b * CAPE;
    for (int i = tid; i < padded; i += 256) esrc[segbase + i] = stage[i];
}

// ---------------- fused layer-1 transforms: A16=(x@w1i)*dinv (bf16), R=x@w1r+b (fp32) ----------------
__global__ void k_mmAR(const float* __restrict__ x,
                       const float* __restrict__ w1i, const float* __restrict__ w1r,
                       const float* __restrict__ b1, const float* __restrict__ dinv,
                       ushort4* __restrict__ A16s, float4* __restrict__ R4, int N) {
    __shared__ float4 Wi[900];   // [3][75][4] float4
    __shared__ float4 Wr[900];
    __shared__ float4 Bs[12];
    const float4* wi4 = (const float4*)w1i;
    const float4* wr4 = (const float4*)w1r;
    for (int i = threadIdx.x; i < 900; i += blockDim.x) { Wi[i] = wi4[i]; Wr[i] = wr4[i]; }
    if (threadIdx.x < 12) Bs[threadIdx.x] = ((const float4*)b1)[threadIdx.x];
    __syncthreads();
    const int total = N * 12;
    const int stride = gridDim.x * blockDim.x;
    for (int idx = blockIdx.x * blockDim.x + threadIdx.x; idx < total; idx += stride) {
        int n = idx / 12;
        int q = idx - n * 12;
        int k = q >> 2, o4 = q & 3;
        const float* xp = x + (size_t)n * 75;
        const float4* wpi = Wi + (k * 75) * 4 + o4;
        const float4* wpr = Wr + (k * 75) * 4 + o4;
        float aix = 0.f, aiy = 0.f, aiz = 0.f, aiw = 0.f;
        float4 br = Bs[q];
        float arx = br.x, ary = br.y, arz = br.z, arw = br.w;
#pragma unroll
        for (int f = 0; f < 75; ++f) {
            float xv = xp[f];
            float4 wi = wpi[f * 4];
            float4 wr = wpr[f * 4];
            aix = fmaf(xv, wi.x, aix);
            aiy = fmaf(xv, wi.y, aiy);
            aiz = fmaf(xv, wi.z, aiz);
            aiw = fmaf(xv, wi.w, aiw);
            arx = fmaf(xv, wr.x, arx);
            ary = fmaf(xv, wr.y, ary);
            arz = fmaf(xv, wr.z, arz);
            arw = fmaf(xv, wr.w, arw);
        }
        float dn = dinv[n];
        ushort4 sa;
        sa.x = f2bf(aix * dn); sa.y = f2bf(aiy * dn);
        sa.z = f2bf(aiz * dn); sa.w = f2bf(aiw * dn);
        A16s[(size_t)n * 12 + q] = sa;
        R4[idx] = make_float4(arx, ary, arz, arw);
    }
}

// ---------------- 48-wide CSR prop over bf16 rows (6 threads/node, uint4 = 8 feats) ----------------
template <int HAS_R, int COMPUTE_S, int SCALE_OUT>
__global__ void k_prop48(const uint4* __restrict__ src, const float4* __restrict__ R4,
                         const int* __restrict__ rowptrp, const int* __restrict__ esrc,
                         const float* __restrict__ dinv, float* __restrict__ sv,
                         uint4* __restrict__ dst, int N) {
    const int total = N * 6;
    const int stride = gridDim.x * blockDim.x;
    for (int idx = blockIdx.x * blockDim.x + threadIdx.x; idx < total; idx += stride) {
        int n = idx / 6;
        int q = idx - n * 6;
        int rp = rowptrp[n];
        int beg = (rp & 0xFFFFF) << 2;
        int end = beg + ((rp >> 20) << 2);
        float a0 = 0.f, a1 = 0.f, a2 = 0.f, a3 = 0.f, a4 = 0.f, a5 = 0.f, a6 = 0.f, a7 = 0.f;
        float sd = 0.f;
        for (int p = beg; p < end; p += 4) {
            int4 e = *(const int4*)(esrc + p);
            uint4 w0 = src[(size_t)e.x * 6 + q];
            uint4 w1 = src[(size_t)e.y * 6 + q];
            uint4 w2 = src[(size_t)e.z * 6 + q];
            uint4 w3 = src[(size_t)e.w * 6 + q];
            a0 += (lo2f(w0.x) + lo2f(w1.x)) + (lo2f(w2.x) + lo2f(w3.x));
            a1 += (hi2f(w0.x) + hi2f(w1.x)) + (hi2f(w2.x) + hi2f(w3.x));
            a2 += (lo2f(w0.y) + lo2f(w1.y)) + (lo2f(w2.y) + lo2f(w3.y));
            a3 += (hi2f(w0.y) + hi2f(w1.y)) + (hi2f(w2.y) + hi2f(w3.y));
            a4 += (lo2f(w0.z) + lo2f(w1.z)) + (lo2f(w2.z) + lo2f(w3.z));
            a5 += (hi2f(w0.z) + hi2f(w1.z)) + (hi2f(w2.z) + hi2f(w3.z));
            a6 += (lo2f(w0.w) + lo2f(w1.w)) + (lo2f(w2.w) + lo2f(w3.w));
            a7 += (hi2f(w0.w) + hi2f(w1.w)) + (hi2f(w2.w) + hi2f(w3.w));
            if (COMPUTE_S) {
                if (q == 0)
                    sd += (dinv[e.x] + dinv[e.y]) + (dinv[e.z] + dinv[e.w]);
            }
        }
        float dn = dinv[n];
        float v0 = a0 * dn, v1 = a1 * dn, v2 = a2 * dn, v3 = a3 * dn;
        float v4 = a4 * dn, v5 = a5 * dn, v6 = a6 * dn, v7 = a7 * dn;
        if (HAS_R) {
            float4 r0 = R4[(size_t)n * 12 + q * 2];
            float4 r1 = R4[(size_t)n * 12 + q * 2 + 1];
            v0 = fmaxf(v0 + r0.x, 0.f); v1 = fmaxf(v1 + r0.y, 0.f);
            v2 = fmaxf(v2 + r0.z, 0.f); v3 = fmaxf(v3 + r0.w, 0.f);
            v4 = fmaxf(v4 + r1.x, 0.f); v5 = fmaxf(v5 + r1.y, 0.f);
            v6 = fmaxf(v6 + r1.z, 0.f); v7 = fmaxf(v7 + r1.w, 0.f);
        }
        if (SCALE_OUT) {
            v0 *= dn; v1 *= dn; v2 *= dn; v3 *= dn;
            v4 *= dn; v5 *= dn; v6 *= dn; v7 *= dn;
        }
        uint4 o;
        o.x = pack2(v0, v1); o.y = pack2(v2, v3);
        o.z = pack2(v4, v5); o.w = pack2(v6, v7);
        dst[(size_t)n * 6 + q] = o;
        if (COMPUTE_S) {
            if (q == 0) sv[n] = sd * dn;
        }
    }
}

// ---------------- layer-1 t=1 epilogue: h1p16 = dinv*mean_k relu(A@w1w+R); z0 = h1.u0 ----------------
__global__ void k_post1(const uint4* __restrict__ A16, const float4* __restrict__ R4,
                        const float* __restrict__ w1w, const float* __restrict__ dinv,
                        const float* __restrict__ u,
                        ushort4* __restrict__ h1p16s, float* __restrict__ z0, int N) {
    __shared__ float4 Ws[192];  // [3][16][4] float4 of w1w[k][i][o]
    const float4* w4 = (const float4*)w1w;
    for (int i = threadIdx.x; i < 192; i += blockDim.x) Ws[i] = w4[i];
    __syncthreads();
    const int total = N * 4;
    const int stride = gridDim.x * blockDim.x;
    for (int idx = blockIdx.x * blockDim.x + threadIdx.x; idx < total; idx += stride) {
        int n = idx >> 2;
        int o4 = idx & 3;
        const uint4* ap = A16 + (size_t)n * 6;
        float av[48];
#pragma unroll
        for (int c6 = 0; c6 < 6; ++c6) {
            uint4 w = ap[c6];
            av[c6 * 8 + 0] = lo2f(w.x); av[c6 * 8 + 1] = hi2f(w.x);
            av[c6 * 8 + 2] = lo2f(w.y); av[c6 * 8 + 3] = hi2f(w.y);
            av[c6 * 8 + 4] = lo2f(w.z); av[c6 * 8 + 5] = hi2f(w.z);
            av[c6 * 8 + 6] = lo2f(w.w); av[c6 * 8 + 7] = hi2f(w.w);
        }
        float4 sum = make_float4(0.f, 0.f, 0.f, 0.f);
#pragma unroll
        for (int k = 0; k < 3; ++k) {
            float4 d = R4[(size_t)n * 12 + k * 4 + o4];
#pragma unroll
            for (int i = 0; i < 16; ++i) {
                float a = av[k * 16 + i];
                float4 w = Ws[(k * 16 + i) * 4 + o4];
                d.x = fmaf(a, w.x, d.x);
                d.y = fmaf(a, w.y, d.y);
                d.z = fmaf(a, w.z, d.z);
                d.w = fmaf(a, w.w, d.w);
            }
            d.x = fmaxf(d.x, 0.f); d.y = fmaxf(d.y, 0.f);
            d.z = fmaxf(d.z, 0.f); d.w = fmaxf(d.w, 0.f);
            sum.x += d.x; sum.y += d.y; sum.z += d.z; sum.w += d.w;
        }
        const float third = 1.0f / 3.0f;
        sum.x *= third; sum.y *= third; sum.z *= third; sum.w *= third;
        float dn = dinv[n];
        ushort4 sp;
        sp.x = f2bf(sum.x * dn); sp.y = f2bf(sum.y * dn);
        sp.z = f2bf(sum.z * dn); sp.w = f2bf(sum.w * dn);
        h1p16s[(size_t)n * 4 + o4] = sp;
        float4 u0q = ((const float4*)u)[o4];
        float part = sum.x * u0q.x + sum.y * u0q.y + sum.z * u0q.z + sum.w * u0q.w;
        part += __shfl_down(part, 2, 4);
        part += __shfl_down(part, 1, 4);
        if (o4 == 0) z0[n] = part;
    }
}

// ---------------- prop16 #1: g1 = A_n h1 (bf16 gather, 2 threads/node); g1p16 + z1 ----------------
__global__ void k_prop16z(const uint4* __restrict__ h1p16,
                          const int* __restrict__ rowptrp, const int* __restrict__ esrc,
                          const float* __restrict__ dinv, const float* __restrict__ u,
                          uint4* __restrict__ g1p16, float* __restrict__ z1, int N) {
    const int total = N * 2;
    const int stride = gridDim.x * blockDim.x;
    for (int idx = blockIdx.x * blockDim.x + threadIdx.x; idx < total; idx += stride) {
        int n = idx >> 1;
        int q = idx & 1;
        int rp = rowptrp[n];
        int beg = (rp & 0xFFFFF) << 2;
        int end = beg + ((rp >> 20) << 2);
        float a0 = 0.f, a1 = 0.f, a2 = 0.f, a3 = 0.f, a4 = 0.f, a5 = 0.f, a6 = 0.f, a7 = 0.f;
        for (int p = beg; p < end; p += 4) {
            int4 e = *(const int4*)(esrc + p);
            uint4 w0 = h1p16[(size_t)e.x * 2 + q];
            uint4 w1 = h1p16[(size_t)e.y * 2 + q];
            uint4 w2 = h1p16[(size_t)e.z * 2 + q];
            uint4 w3 = h1p16[(size_t)e.w * 2 + q];
            a0 += (lo2f(w0.x) + lo2f(w1.x)) + (lo2f(w2.x) + lo2f(w3.x));
            a1 += (hi2f(w0.x) + hi2f(w1.x)) + (hi2f(w2.x) + hi2f(w3.x));
            a2 += (lo2f(w0.y) + lo2f(w1.y)) + (lo2f(w2.y) + lo2f(w3.y));
            a3 += (hi2f(w0.y) + hi2f(w1.y)) + (hi2f(w2.y) + hi2f(w3.y));
            a4 += (lo2f(w0.z) + lo2f(w1.z)) + (lo2f(w2.z) + lo2f(w3.z));
            a5 += (hi2f(w0.z) + hi2f(w1.z)) + (hi2f(w2.z) + hi2f(w3.z));
            a6 += (lo2f(w0.w) + lo2f(w1.w)) + (lo2f(w2.w) + lo2f(w3.w));
            a7 += (hi2f(w0.w) + hi2f(w1.w)) + (hi2f(w2.w) + hi2f(w3.w));
        }
        float dn = dinv[n];
        float v0 = a0 * dn, v1 = a1 * dn, v2 = a2 * dn, v3 = a3 * dn;
        float v4 = a4 * dn, v5 = a5 * dn, v6 = a6 * dn, v7 = a7 * dn;
        uint4 o;
        o.x = pack2(v0 * dn, v1 * dn); o.y = pack2(v2 * dn, v3 * dn);
        o.z = pack2(v4 * dn, v5 * dn); o.w = pack2(v6 * dn, v7 * dn);
        g1p16[(size_t)n * 2 + q] = o;
        const float4* u4 = (const float4*)(u + 16);
        float4 ua = u4[q * 2], ub = u4[q * 2 + 1];
        float part = v0 * ua.x + v1 * ua.y + v2 * ua.z + v3 * ua.w
                   + v4 * ub.x + v5 * ub.y + v6 * ub.z + v7 * ub.w;
        part += __shfl_down(part, 1, 2);
        if (q == 0) z1[n] = part;
    }
}

// ---------------- prop16 #2 fused with score/pool: g2 in-register ----------------
__global__ void k_score(const uint4* __restrict__ g1p16,
                        const int* __restrict__ rowptrp, const int* __restrict__ esrc,
                        const float* __restrict__ dinv, const float* __restrict__ u,
                        const float* __restrict__ z0, const float* __restrict__ z1,
                        const float* __restrict__ sv, const int* __restrict__ batch,
                        float* __restrict__ out, int N) {
    const int total = N * 2;
    const int stride = gridDim.x * blockDim.x;
    for (int idx = blockIdx.x * blockDim.x + threadIdx.x; idx < total; idx += stride) {
        int n = idx >> 1;
        int q = idx & 1;
        int rp = rowptrp[n];
        int beg = (rp & 0xFFFFF) << 2;
        int end = beg + ((rp >> 20) << 2);
        float a0 = 0.f, a1 = 0.f, a2 = 0.f, a3 = 0.f, a4 = 0.f, a5 = 0.f, a6 = 0.f, a7 = 0.f;
        for (int p = beg; p < end; p += 4) {
            int4 e = *(const int4*)(esrc + p);
            uint4 w0 = g1p16[(size_t)e.x * 2 + q];
            uint4 w1 = g1p16[(size_t)e.y * 2 + q];
            uint4 w2 = g1p16[(size_t)e.z * 2 + q];
            uint4 w3 = g1p16[(size_t)e.w * 2 + q];
            a0 += (lo2f(w0.x) + lo2f(w1.x)) + (lo2f(w2.x) + lo2f(w3.x));
            a1 += (hi2f(w0.x) + hi2f(w1.x)) + (hi2f(w2.x) + hi2f(w3.x));
            a2 += (lo2f(w0.y) + lo2f(w1.y)) + (lo2f(w2.y) + lo2f(w3.y));
            a3 += (hi2f(w0.y) + hi2f(w1.y)) + (hi2f(w2.y) + hi2f(w3.y));
            a4 += (lo2f(w0.z) + lo2f(w1.z)) + (lo2f(w2.z) + lo2f(w3.z));
            a5 += (hi2f(w0.z) + hi2f(w1.z)) + (hi2f(w2.z) + hi2f(w3.z));
            a6 += (lo2f(w0.w) + lo2f(w1.w)) + (lo2f(w2.w) + lo2f(w3.w));
            a7 += (hi2f(w0.w) + hi2f(w1.w)) + (hi2f(w2.w) + hi2f(w3.w));
        }
        float dn = dinv[n];
        const float4* u4 = (const float4*)(u + 32);
        float4 ua = u4[q * 2], ub = u4[q * 2 + 1];
        float part = (a0 * dn) * ua.x + (a1 * dn) * ua.y + (a2 * dn) * ua.z + (a3 * dn) * ua.w
                   + (a4 * dn) * ub.x + (a5 * dn) * ub.y + (a6 * dn) * ub.z + (a7 * dn) * ub.w;
        part += __shfl_down(part, 1, 2);
        if (q == 0) {
            float v = part + z0[n] + z1[n] + sv[n] * u[48] + u[49];
            atomicAdd(&out[batch[n]], v);
        }
    }
}

// ---------------- precombine layer-2+head weights; blocks 1..8 init out ----------------
__global__ void k_comb(const float* __restrict__ w2i, const float* __restrict__ w2w,
                       const float* __restrict__ w2r, const float* __restrict__ b2,
                       const float* __restrict__ wg, const float* __restrict__ bg,
                       float* __restrict__ u, float* __restrict__ out) {
    if (blockIdx.x > 0) {
        int g = (blockIdx.x - 1) * 256 + threadIdx.x;
        if (g < NG) out[g] = bg[0];
        return;
    }
    __shared__ float t[3][64];
    int tid = threadIdx.x;
    if (tid < 64) {
#pragma unroll
        for (int k = 0; k < 3; ++k) {
            float a = 0.f;
            for (int j = 0; j < 64; ++j) a = fmaf(w2w[k * 4096 + tid * 64 + j], wg[j], a);
            t[k][tid] = a;
        }
    }
    __syncthreads();
    if (tid < 64) {
        float wgv = wg[tid];
        float tk0 = t[0][tid], tk1 = t[1][tid], tk2 = t[2][tid];
        const float third = 1.0f / 3.0f;
        for (int j = 0; j < 16; ++j) {
            float wi0 = w2i[j * 64 + tid], wi1 = w2i[1024 + j * 64 + tid], wi2 = w2i[2048 + j * 64 + tid];
            float wr0 = w2r[j * 64 + tid], wr1 = w2r[1024 + j * 64 + tid], wr2 = w2r[2048 + j * 64 + tid];
            float a2 = wi0 * tk0 + wi1 * tk1 + wi2 * tk2;
            float a1 = wr0 * tk0 + wr1 * tk1 + wr2 * tk2;
            float a0 = (wr0 + wr1 + wr2) * wgv;
#pragma unroll
            for (int off = 32; off > 0; off >>= 1) {
                a2 += __shfl_down(a2, off, 64);
                a1 += __shfl_down(a1, off, 64);
                a0 += __shfl_down(a0, off, 64);
            }
            if (tid == 0) {
                u[j] = a0 * third;
                u[16 + j] = a1 * third;
                u[32 + j] = a2 * third;
            }
        }
        float b0 = b2[tid], b1v = b2[64 + tid], b2v = b2[128 + tid];
        float c0 = b0 * tk0 + b1v * tk1 + b2v * tk2;
        float c1 = (b0 + b1v + b2v) * wgv;
#pragma unroll
        for (int off = 32; off > 0; off >>= 1) {
            c0 += __shfl_down(c0, off, 64);
            c1 += __shfl_down(c1, off, 64);
        }
        if (tid == 0) {
            u[48] = c0 * third;
            u[49] = c1 * third;
        }
    }
}

extern "C" void kernel_launch(void* const* d_in, const int* in_sizes, int n_in,
                              void* d_out, int out_size, void* d_ws, size_t ws_size,
                              hipStream_t stream) {
    const float* x   = (const float*)d_in[0];
    const int*   ei  = (const int*)d_in[1];
    const int*   row = ei;
    const int*   col = ei + NE;
    const int*   batch = (const int*)d_in[2];
    const float* w1i = (const float*)d_in[3];
    const float* w1w = (const float*)d_in[4];
    const float* w1r = (const float*)d_in[5];
    const float* w1b = (const float*)d_in[6];
    const float* w2i = (const float*)d_in[7];
    const float* w2w = (const float*)d_in[8];
    const float* w2r = (const float*)d_in[9];
    const float* w2b = (const float*)d_in[10];
    const float* wg  = (const float*)d_in[11];
    const float* bg  = (const float*)d_in[12];
    float* out = (float*)d_out;

    // workspace layout (all 16B-aligned)
    uint4* A16   = (uint4*)d_ws;                          // [(N+1)*6] uint4 = bf16[N+1][48]
    uint4* B16   = A16 + (size_t)(NN + 1) * 6;            // same
    float* R     = (float*)(B16 + (size_t)(NN + 1) * 6);  // fp32 [N][48]
    uint4* h1p16 = (uint4*)(R + (size_t)NN * 48);         // [(N+1)*2] uint4 = bf16[N+1][16]
    uint4* g1p16 = h1p16 + (size_t)(NN + 1) * 2;          // same
    float* dinv  = (float*)(g1p16 + (size_t)(NN + 1) * 2);// [N+1] pad to 100004
    float* sv    = dinv + 100004;                         // [N]
    float* z0    = sv + NN;                               // [N]
    float* z1    = z0 + NN;                               // [N]
    float* u     = z1 + NN;                               // [64]
    int*   rowptrp = (int*)(u + 64);                      // [N] packed
    int*   gcur  = rowptrp + NN;                          // [512]
    int*   pairs = gcur + 512;                            // [(NBK+1)*CAPQ]
    int*   esrc  = pairs + (size_t)(NBK + 1) * CAPQ;      // [NBK*CAPE]

    const int T = 256;

    // ---- CSR build (histogram-free, bucketed) ----
    k_init<<<3, T, 0, stream>>>(gcur, A16, B16, h1p16, g1p16, dinv);
    k_part<<<128, T, 0, stream>>>(row, col, gcur, pairs, NE);
    k_bucket<<<NBK, T, 0, stream>>>(pairs, gcur, esrc, rowptrp, dinv, NN);

    // ---- precombined layer-2+head weights + out init ----
    k_comb<<<9, T, 0, stream>>>(w2i, w2w, w2r, w2b, wg, bg, u, out);

    // ---- layer 1 input transforms ----
    k_mmAR<<<2048, T, 0, stream>>>(x, w1i, w1r, w1b, dinv, (ushort4*)A16, (float4*)R, NN);

    // t=0: B16 = bf16( dinv * relu(prop(A16) + R) * dinv ); also sv
    k_prop48<1, 1, 1><<<cdiv((long long)NN * 6, T), T, 0, stream>>>(
        A16, (const float4*)R, rowptrp, esrc, dinv, sv, B16, NN);
    // t=1 agg: A16 = bf16( dinv * prop(B16) )
    k_prop48<0, 0, 0><<<cdiv((long long)NN * 6, T), T, 0, stream>>>(
        B16, nullptr, rowptrp, esrc, dinv, nullptr, A16, NN);
    // h1p16 = bf16(dinv * mean_k relu(A@w1w + R)); z0 = h1.u0
    k_post1<<<cdiv((long long)NN * 4, T), T, 0, stream>>>(
        A16, (const float4*)R, w1w, dinv, u, (ushort4*)h1p16, z0, NN);

    // ---- layer 2 (linearized): g1p16 + z1, then fused g2+score+pool ----
    k_prop16z<<<cdiv((long long)NN * 2, T), T, 0, stream>>>(
        h1p16, rowptrp, esrc, dinv, u, g1p16, z1, NN);
    k_score<<<cdiv((long long)NN * 2, T), T, 0, stream>>>(
        g1p16, rowptrp, esrc, dinv, u, z0, z1, sv, batch, out, NN);
}

// Round 10
// 210.190 us; speedup vs baseline: 7.2357x; 1.0563x over previous
//
#include <hip/hip_runtime.h>

#define NN 100000
#define NE 1200000
#define NG 2048
#define NBK 391           // cdiv(NN,256) buckets of 256 nodes
#define CAPQ 4096         // raw records capacity per bucket (mean 3070, >18 sigma)
#define CAPE 5120         // padded CSR capacity per bucket

static inline int cdiv(long long a, int b) { return (int)((a + b - 1) / b); }

// ---------------- bf16 helpers (RNE pack, shift unpack) ----------------
__device__ __forceinline__ unsigned short f2bf(float f) {
    unsigned int u = __float_as_uint(f);
    u += 0x7fffu + ((u >> 16) & 1u);
    return (unsigned short)(u >> 16);
}
__device__ __forceinline__ unsigned int pack2(float a, float b) {
    return (unsigned int)f2bf(a) | ((unsigned int)f2bf(b) << 16);
}
__device__ __forceinline__ float lo2f(unsigned int w) { return __uint_as_float(w << 16); }
__device__ __forceinline__ float hi2f(unsigned int w) { return __uint_as_float(w & 0xffff0000u); }

// ---------------- init: bucket cursors + sentinel rows ----------------
__global__ void k_init(int* __restrict__ gcur, uint4* __restrict__ A16,
                       uint4* __restrict__ B16, uint4* __restrict__ h1p16,
                       uint4* __restrict__ g1p16, float* __restrict__ dinv) {
    int g = blockIdx.x * blockDim.x + threadIdx.x;
    if (g < NBK) gcur[g] = g * CAPQ;
    if (g == NBK) dinv[NN] = 0.f;
    uint4 z = make_uint4(0u, 0u, 0u, 0u);
    int s = g - 512;
    if (s >= 0 && s < 6) {
        A16[(size_t)NN * 6 + s] = z;
        B16[(size_t)NN * 6 + s] = z;
    } else if (s >= 6 && s < 8) {
        h1p16[(size_t)NN * 2 + (s - 6)] = z;
        g1p16[(size_t)NN * 2 + (s - 6)] = z;
    }
}

// ---------------- phase 1: partition edges bucket-major into pairs (int4, 512 blocks) ----------------
__global__ __launch_bounds__(256) void k_part(const int4* __restrict__ row4,
                                              const int4* __restrict__ col4,
                                              int* __restrict__ gcur,
                                              int* __restrict__ pairs, int E4) {
    __shared__ int hcnt[NBK];
    __shared__ int hbase[NBK];
    int chunk = (E4 + gridDim.x - 1) / gridDim.x;
    int beg = blockIdx.x * chunk;
    int end = min(E4, beg + chunk);
    for (int j = threadIdx.x; j < NBK; j += 256) hcnt[j] = 0;
    __syncthreads();
    for (int g = beg + threadIdx.x; g < end; g += 256) {
        int4 c = col4[g];
        atomicAdd(&hcnt[c.x >> 8], 1);
        atomicAdd(&hcnt[c.y >> 8], 1);
        atomicAdd(&hcnt[c.z >> 8], 1);
        atomicAdd(&hcnt[c.w >> 8], 1);
    }
    __syncthreads();
    for (int j = threadIdx.x; j < NBK; j += 256) {
        int c = hcnt[j];
        hbase[j] = c > 0 ? atomicAdd(&gcur[j], c) : 0;
        hcnt[j] = 0;
    }
    __syncthreads();
    for (int g = beg + threadIdx.x; g < end; g += 256) {
        int4 c = col4[g];
        int4 r = row4[g];
        int b0 = c.x >> 8, b1 = c.y >> 8, b2 = c.z >> 8, b3 = c.w >> 8;
        int p0 = hbase[b0] + atomicAdd(&hcnt[b0], 1);
        if (p0 < (b0 + 1) * CAPQ) pairs[p0] = ((c.x & 255) << 17) | r.x;
        int p1 = hbase[b1] + atomicAdd(&hcnt[b1], 1);
        if (p1 < (b1 + 1) * CAPQ) pairs[p1] = ((c.y & 255) << 17) | r.y;
        int p2 = hbase[b2] + atomicAdd(&hcnt[b2], 1);
        if (p2 < (b2 + 1) * CAPQ) pairs[p2] = ((c.z & 255) << 17) | r.z;
        int p3 = hbase[b3] + atomicAdd(&hcnt[b3], 1);
        if (p3 < (b3 + 1) * CAPQ) pairs[p3] = ((c.w & 255) << 17) | r.w;
    }
}

// ---------------- phase 2: per-bucket count/scan/dinv/rowptr + staged scatter (int4) ----------------
// packed rowptr: bits[0:20) = beg>>2, bits[20:31) = paddedCount>>2
__global__ __launch_bounds__(256) void k_bucket(const int* __restrict__ pairs,
                                                const int* __restrict__ gcur,
                                                int* __restrict__ esrc,
                                                int* __restrict__ rowptrp,
                                                float* __restrict__ dinv, int N) {
    __shared__ int stage[CAPE];
    __shared__ int lcnt[256];
    __shared__ int s[256];
    __shared__ int tot;
    int b = blockIdx.x;
    int base = b << 8;
    int nn = min(256, N - base);
    int qb = b * CAPQ;
    int qe = min(gcur[b], qb + CAPQ);
    int cnt = qe - qb;
    int n4 = cnt >> 2, tail = cnt & 3;
    const int4* pairs4 = (const int4*)(pairs + qb);
    int tid = threadIdx.x;
    lcnt[tid] = 0;
    __syncthreads();
    for (int g = tid; g < n4; g += 256) {
        int4 v = pairs4[g];
        atomicAdd(&lcnt[v.x >> 17], 1);
        atomicAdd(&lcnt[v.y >> 17], 1);
        atomicAdd(&lcnt[v.z >> 17], 1);
        atomicAdd(&lcnt[v.w >> 17], 1);
    }
    if (tid < tail) atomicAdd(&lcnt[pairs[qb + n4 * 4 + tid] >> 17], 1);
    __syncthreads();
    int c = lcnt[tid];
    int pc = (c + 3) & ~3;
    s[tid] = pc;
    __syncthreads();
    for (int off = 1; off < 256; off <<= 1) {
        int t = (tid >= off) ? s[tid - off] : 0;
        __syncthreads();
        s[tid] += t;
        __syncthreads();
    }
    int myofs = s[tid] - pc;
    if (tid == 255) tot = s[255];
    __syncthreads();
    int padded = tot;
    if (tid < nn) {
        dinv[base + tid] = c > 0 ? rsqrtf((float)c) : 0.f;
        rowptrp[base + tid] = ((b * CAPE + myofs) >> 2) | ((pc >> 2) << 20);
    }
    int4* stage4 = (int4*)stage;
    int pad4 = padded >> 2;
    int4 sent = make_int4(N, N, N, N);
    for (int i = tid; i < pad4; i += 256) stage4[i] = sent;
    lcnt[tid] = myofs;
    __syncthreads();
    for (int g = tid; g < n4; g += 256) {
        int4 v = pairs4[g];
        int pos;
        pos = atomicAdd(&lcnt[v.x >> 17], 1); stage[pos] = v.x & 0x1FFFF;
        pos = atomicAdd(&lcnt[v.y >> 17], 1); stage[pos] = v.y & 0x1FFFF;
        pos = atomicAdd(&lcnt[v.z >> 17], 1); stage[pos] = v.z & 0x1FFFF;
        pos = atomicAdd(&lcnt[v.w >> 17], 1); stage[pos] = v.w & 0x1FFFF;
    }
    if (tid < tail) {
        int v = pairs[qb + n4 * 4 + tid];
        int pos = atomicAdd(&lcnt[v >> 17], 1);
        stage[pos] = v & 0x1FFFF;
    }
    __syncthreads();
    int4* esrc4 = (int4*)(esrc + b * CAPE);
    for (int i = tid; i < pad4; i += 256) esrc4[i] = stage4[i];
}

// ---------------- fused layer-1 transforms: A16=(x@w1i)*dinv (bf16), R=x@w1r+b (fp32) ----------------
__global__ void k_mmAR(const float* __restrict__ x,
                       const float* __restrict__ w1i, const float* __restrict__ w1r,
                       const float* __restrict__ b1, const float* __restrict__ dinv,
                       ushort4* __restrict__ A16s, float4* __restrict__ R4, int N) {
    __shared__ float4 Wi[900];   // [3][75][4] float4
    __shared__ float4 Wr[900];
    __shared__ float4 Bs[12];
    const float4* wi4 = (const float4*)w1i;
    const float4* wr4 = (const float4*)w1r;
    for (int i = threadIdx.x; i < 900; i += blockDim.x) { Wi[i] = wi4[i]; Wr[i] = wr4[i]; }
    if (threadIdx.x < 12) Bs[threadIdx.x] = ((const float4*)b1)[threadIdx.x];
    __syncthreads();
    const int total = N * 12;
    const int stride = gridDim.x * blockDim.x;
    for (int idx = blockIdx.x * blockDim.x + threadIdx.x; idx < total; idx += stride) {
        int n = idx / 12;
        int q = idx - n * 12;
        int k = q >> 2, o4 = q & 3;
        const float* xp = x + (size_t)n * 75;
        const float4* wpi = Wi + (k * 75) * 4 + o4;
        const float4* wpr = Wr + (k * 75) * 4 + o4;
        float aix = 0.f, aiy = 0.f, aiz = 0.f, aiw = 0.f;
        float4 br = Bs[q];
        float arx = br.x, ary = br.y, arz = br.z, arw = br.w;
#pragma unroll
        for (int f = 0; f < 75; ++f) {
            float xv = xp[f];
            float4 wi = wpi[f * 4];
            float4 wr = wpr[f * 4];
            aix = fmaf(xv, wi.x, aix);
            aiy = fmaf(xv, wi.y, aiy);
            aiz = fmaf(xv, wi.z, aiz);
            aiw = fmaf(xv, wi.w, aiw);
            arx = fmaf(xv, wr.x, arx);
            ary = fmaf(xv, wr.y, ary);
            arz = fmaf(xv, wr.z, arz);
            arw = fmaf(xv, wr.w, arw);
        }
        float dn = dinv[n];
        ushort4 sa;
        sa.x = f2bf(aix * dn); sa.y = f2bf(aiy * dn);
        sa.z = f2bf(aiz * dn); sa.w = f2bf(aiw * dn);
        A16s[(size_t)n * 12 + q] = sa;
        R4[idx] = make_float4(arx, ary, arz, arw);
    }
}

// ---------------- 48-wide CSR prop over bf16 rows (6 threads/node, uint4 = 8 feats) ----------------
template <int HAS_R, int COMPUTE_S, int SCALE_OUT>
__global__ void k_prop48(const uint4* __restrict__ src, const float4* __restrict__ R4,
                         const int* __restrict__ rowptrp, const int* __restrict__ esrc,
                         const float* __restrict__ dinv, float* __restrict__ sv,
                         uint4* __restrict__ dst, int N) {
    const int total = N * 6;
    const int stride = gridDim.x * blockDim.x;
    for (int idx = blockIdx.x * blockDim.x + threadIdx.x; idx < total; idx += stride) {
        int n = idx / 6;
        int q = idx - n * 6;
        int rp = rowptrp[n];
        int beg = (rp & 0xFFFFF) << 2;
        int end = beg + ((rp >> 20) << 2);
        float a0 = 0.f, a1 = 0.f, a2 = 0.f, a3 = 0.f, a4 = 0.f, a5 = 0.f, a6 = 0.f, a7 = 0.f;
        float sd = 0.f;
        for (int p = beg; p < end; p += 4) {
            int4 e = *(const int4*)(esrc + p);
            uint4 w0 = src[(size_t)e.x * 6 + q];
            uint4 w1 = src[(size_t)e.y * 6 + q];
            uint4 w2 = src[(size_t)e.z * 6 + q];
            uint4 w3 = src[(size_t)e.w * 6 + q];
            a0 += (lo2f(w0.x) + lo2f(w1.x)) + (lo2f(w2.x) + lo2f(w3.x));
            a1 += (hi2f(w0.x) + hi2f(w1.x)) + (hi2f(w2.x) + hi2f(w3.x));
            a2 += (lo2f(w0.y) + lo2f(w1.y)) + (lo2f(w2.y) + lo2f(w3.y));
            a3 += (hi2f(w0.y) + hi2f(w1.y)) + (hi2f(w2.y) + hi2f(w3.y));
            a4 += (lo2f(w0.z) + lo2f(w1.z)) + (lo2f(w2.z) + lo2f(w3.z));
            a5 += (hi2f(w0.z) + hi2f(w1.z)) + (hi2f(w2.z) + hi2f(w3.z));
            a6 += (lo2f(w0.w) + lo2f(w1.w)) + (lo2f(w2.w) + lo2f(w3.w));
            a7 += (hi2f(w0.w) + hi2f(w1.w)) + (hi2f(w2.w) + hi2f(w3.w));
            if (COMPUTE_S) {
                if (q == 0)
                    sd += (dinv[e.x] + dinv[e.y]) + (dinv[e.z] + dinv[e.w]);
            }
        }
        float dn = dinv[n];
        float v0 = a0 * dn, v1 = a1 * dn, v2 = a2 * dn, v3 = a3 * dn;
        float v4 = a4 * dn, v5 = a5 * dn, v6 = a6 * dn, v7 = a7 * dn;
        if (HAS_R) {
            float4 r0 = R4[(size_t)n * 12 + q * 2];
            float4 r1 = R4[(size_t)n * 12 + q * 2 + 1];
            v0 = fmaxf(v0 + r0.x, 0.f); v1 = fmaxf(v1 + r0.y, 0.f);
            v2 = fmaxf(v2 + r0.z, 0.f); v3 = fmaxf(v3 + r0.w, 0.f);
            v4 = fmaxf(v4 + r1.x, 0.f); v5 = fmaxf(v5 + r1.y, 0.f);
            v6 = fmaxf(v6 + r1.z, 0.f); v7 = fmaxf(v7 + r1.w, 0.f);
        }
        if (SCALE_OUT) {
            v0 *= dn; v1 *= dn; v2 *= dn; v3 *= dn;
            v4 *= dn; v5 *= dn; v6 *= dn; v7 *= dn;
        }
        uint4 o;
        o.x = pack2(v0, v1); o.y = pack2(v2, v3);
        o.z = pack2(v4, v5); o.w = pack2(v6, v7);
        dst[(size_t)n * 6 + q] = o;
        if (COMPUTE_S) {
            if (q == 0) sv[n] = sd * dn;
        }
    }
}

// ---------------- layer-1 t=1 epilogue: h1p16 = dinv*mean_k relu(A@w1w+R); z0 = h1.u0 ----------------
__global__ void k_post1(const uint4* __restrict__ A16, const float4* __restrict__ R4,
                        const float* __restrict__ w1w, const float* __restrict__ dinv,
                        const float* __restrict__ u,
                        ushort4* __restrict__ h1p16s, float* __restrict__ z0, int N) {
    __shared__ float4 Ws[192];  // [3][16][4] float4 of w1w[k][i][o]
    const float4* w4 = (const float4*)w1w;
    for (int i = threadIdx.x; i < 192; i += blockDim.x) Ws[i] = w4[i];
    __syncthreads();
    const int total = N * 4;
    const int stride = gridDim.x * blockDim.x;
    for (int idx = blockIdx.x * blockDim.x + threadIdx.x; idx < total; idx += stride) {
        int n = idx >> 2;
        int o4 = idx & 3;
        const uint4* ap = A16 + (size_t)n * 6;
        float av[48];
#pragma unroll
        for (int c6 = 0; c6 < 6; ++c6) {
            uint4 w = ap[c6];
            av[c6 * 8 + 0] = lo2f(w.x); av[c6 * 8 + 1] = hi2f(w.x);
            av[c6 * 8 + 2] = lo2f(w.y); av[c6 * 8 + 3] = hi2f(w.y);
            av[c6 * 8 + 4] = lo2f(w.z); av[c6 * 8 + 5] = hi2f(w.z);
            av[c6 * 8 + 6] = lo2f(w.w); av[c6 * 8 + 7] = hi2f(w.w);
        }
        float4 sum = make_float4(0.f, 0.f, 0.f, 0.f);
#pragma unroll
        for (int k = 0; k < 3; ++k) {
            float4 d = R4[(size_t)n * 12 + k * 4 + o4];
#pragma unroll
            for (int i = 0; i < 16; ++i) {
                float a = av[k * 16 + i];
                float4 w = Ws[(k * 16 + i) * 4 + o4];
                d.x = fmaf(a, w.x, d.x);
                d.y = fmaf(a, w.y, d.y);
                d.z = fmaf(a, w.z, d.z);
                d.w = fmaf(a, w.w, d.w);
            }
            d.x = fmaxf(d.x, 0.f); d.y = fmaxf(d.y, 0.f);
            d.z = fmaxf(d.z, 0.f); d.w = fmaxf(d.w, 0.f);
            sum.x += d.x; sum.y += d.y; sum.z += d.z; sum.w += d.w;
        }
        const float third = 1.0f / 3.0f;
        sum.x *= third; sum.y *= third; sum.z *= third; sum.w *= third;
        float dn = dinv[n];
        ushort4 sp;
        sp.x = f2bf(sum.x * dn); sp.y = f2bf(sum.y * dn);
        sp.z = f2bf(sum.z * dn); sp.w = f2bf(sum.w * dn);
        h1p16s[(size_t)n * 4 + o4] = sp;
        float4 u0q = ((const float4*)u)[o4];
        float part = sum.x * u0q.x + sum.y * u0q.y + sum.z * u0q.z + sum.w * u0q.w;
        part += __shfl_down(part, 2, 4);
        part += __shfl_down(part, 1, 4);
        if (o4 == 0) z0[n] = part;
    }
}

// ---------------- prop16 #1: g1 = A_n h1 (bf16 gather, 2 threads/node); g1p16 + z1 ----------------
__global__ void k_prop16z(const uint4* __restrict__ h1p16,
                          const int* __restrict__ rowptrp, const int* __restrict__ esrc,
                          const float* __restrict__ dinv, const float* __restrict__ u,
                          uint4* __restrict__ g1p16, float* __restrict__ z1, int N) {
    const int total = N * 2;
    const int stride = gridDim.x * blockDim.x;
    for (int idx = blockIdx.x * blockDim.x + threadIdx.x; idx < total; idx += stride) {
        int n = idx >> 1;
        int q = idx & 1;
        int rp = rowptrp[n];
        int beg = (rp & 0xFFFFF) << 2;
        int end = beg + ((rp >> 20) << 2);
        float a0 = 0.f, a1 = 0.f, a2 = 0.f, a3 = 0.f, a4 = 0.f, a5 = 0.f, a6 = 0.f, a7 = 0.f;
        for (int p = beg; p < end; p += 4) {
            int4 e = *(const int4*)(esrc + p);
            uint4 w0 = h1p16[(size_t)e.x * 2 + q];
            uint4 w1 = h1p16[(size_t)e.y * 2 + q];
            uint4 w2 = h1p16[(size_t)e.z * 2 + q];
            uint4 w3 = h1p16[(size_t)e.w * 2 + q];
            a0 += (lo2f(w0.x) + lo2f(w1.x)) + (lo2f(w2.x) + lo2f(w3.x));
            a1 += (hi2f(w0.x) + hi2f(w1.x)) + (hi2f(w2.x) + hi2f(w3.x));
            a2 += (lo2f(w0.y) + lo2f(w1.y)) + (lo2f(w2.y) + lo2f(w3.y));
            a3 += (hi2f(w0.y) + hi2f(w1.y)) + (hi2f(w2.y) + hi2f(w3.y));
            a4 += (lo2f(w0.z) + lo2f(w1.z)) + (lo2f(w2.z) + lo2f(w3.z));
            a5 += (hi2f(w0.z) + hi2f(w1.z)) + (hi2f(w2.z) + hi2f(w3.z));
            a6 += (lo2f(w0.w) + lo2f(w1.w)) + (lo2f(w2.w) + lo2f(w3.w));
            a7 += (hi2f(w0.w) + hi2f(w1.w)) + (hi2f(w2.w) + hi2f(w3.w));
        }
        float dn = dinv[n];
        float v0 = a0 * dn, v1 = a1 * dn, v2 = a2 * dn, v3 = a3 * dn;
        float v4 = a4 * dn, v5 = a5 * dn, v6 = a6 * dn, v7 = a7 * dn;
        uint4 o;
        o.x = pack2(v0 * dn, v1 * dn); o.y = pack2(v2 * dn, v3 * dn);
        o.z = pack2(v4 * dn, v5 * dn); o.w = pack2(v6 * dn, v7 * dn);
        g1p16[(size_t)n * 2 + q] = o;
        const float4* u4 = (const float4*)(u + 16);
        float4 ua = u4[q * 2], ub = u4[q * 2 + 1];
        float part = v0 * ua.x + v1 * ua.y + v2 * ua.z + v3 * ua.w
                   + v4 * ub.x + v5 * ub.y + v6 * ub.z + v7 * ub.w;
        part += __shfl_down(part, 1, 2);
        if (q == 0) z1[n] = part;
    }
}

// ---------------- prop16 #2 fused with score/pool: g2 in-register ----------------
__global__ void k_score(const uint4* __restrict__ g1p16,
                        const int* __restrict__ rowptrp, const int* __restrict__ esrc,
                        const float* __restrict__ dinv, const float* __restrict__ u,
                        const float* __restrict__ z0, const float* __restrict__ z1,
                        const float* __restrict__ sv, const int* __restrict__ batch,
                        float* __restrict__ out, int N) {
    const int total = N * 2;
    const int stride = gridDim.x * blockDim.x;
    for (int idx = blockIdx.x * blockDim.x + threadIdx.x; idx < total; idx += stride) {
        int n = idx >> 1;
        int q = idx & 1;
        int rp = rowptrp[n];
        int beg = (rp & 0xFFFFF) << 2;
        int end = beg + ((rp >> 20) << 2);
        float a0 = 0.f, a1 = 0.f, a2 = 0.f, a3 = 0.f, a4 = 0.f, a5 = 0.f, a6 = 0.f, a7 = 0.f;
        for (int p = beg; p < end; p += 4) {
            int4 e = *(const int4*)(esrc + p);
            uint4 w0 = g1p16[(size_t)e.x * 2 + q];
            uint4 w1 = g1p16[(size_t)e.y * 2 + q];
            uint4 w2 = g1p16[(size_t)e.z * 2 + q];
            uint4 w3 = g1p16[(size_t)e.w * 2 + q];
            a0 += (lo2f(w0.x) + lo2f(w1.x)) + (lo2f(w2.x) + lo2f(w3.x));
            a1 += (hi2f(w0.x) + hi2f(w1.x)) + (hi2f(w2.x) + hi2f(w3.x));
            a2 += (lo2f(w0.y) + lo2f(w1.y)) + (lo2f(w2.y) + lo2f(w3.y));
            a3 += (hi2f(w0.y) + hi2f(w1.y)) + (hi2f(w2.y) + hi2f(w3.y));
            a4 += (lo2f(w0.z) + lo2f(w1.z)) + (lo2f(w2.z) + lo2f(w3.z));
            a5 += (hi2f(w0.z) + hi2f(w1.z)) + (hi2f(w2.z) + hi2f(w3.z));
            a6 += (lo2f(w0.w) + lo2f(w1.w)) + (lo2f(w2.w) + lo2f(w3.w));
            a7 += (hi2f(w0.w) + hi2f(w1.w)) + (hi2f(w2.w) + hi2f(w3.w));
        }
        float dn = dinv[n];
        const float4* u4 = (const float4*)(u + 32);
        float4 ua = u4[q * 2], ub = u4[q * 2 + 1];
        float part = (a0 * dn) * ua.x + (a1 * dn) * ua.y + (a2 * dn) * ua.z + (a3 * dn) * ua.w
                   + (a4 * dn) * ub.x + (a5 * dn) * ub.y + (a6 * dn) * ub.z + (a7 * dn) * ub.w;
        part += __shfl_down(part, 1, 2);
        if (q == 0) {
            float v = part + z0[n] + z1[n] + sv[n] * u[48] + u[49];
            atomicAdd(&out[batch[n]], v);
        }
    }
}

// ---------------- precombine layer-2+head weights; blocks 1..8 init out ----------------
__global__ void k_comb(const float* __restrict__ w2i, const float* __restrict__ w2w,
                       const float* __restrict__ w2r, const float* __restrict__ b2,
                       const float* __restrict__ wg, const float* __restrict__ bg,
                       float* __restrict__ u, float* __restrict__ out) {
    if (blockIdx.x > 0) {
        int g = (blockIdx.x - 1) * 256 + threadIdx.x;
        if (g < NG) out[g] = bg[0];
        return;
    }
    __shared__ float t[3][64];
    int tid = threadIdx.x;
    if (tid < 64) {
#pragma unroll
        for (int k = 0; k < 3; ++k) {
            float a = 0.f;
            for (int j = 0; j < 64; ++j) a = fmaf(w2w[k * 4096 + tid * 64 + j], wg[j], a);
            t[k][tid] = a;
        }
    }
    __syncthreads();
    if (tid < 64) {
        float wgv = wg[tid];
        float tk0 = t[0][tid], tk1 = t[1][tid], tk2 = t[2][tid];
        const float third = 1.0f / 3.0f;
        for (int j = 0; j < 16; ++j) {
            float wi0 = w2i[j * 64 + tid], wi1 = w2i[1024 + j * 64 + tid], wi2 = w2i[2048 + j * 64 + tid];
            float wr0 = w2r[j * 64 + tid], wr1 = w2r[1024 + j * 64 + tid], wr2 = w2r[2048 + j * 64 + tid];
            float a2 = wi0 * tk0 + wi1 * tk1 + wi2 * tk2;
            float a1 = wr0 * tk0 + wr1 * tk1 + wr2 * tk2;
            float a0 = (wr0 + wr1 + wr2) * wgv;
#pragma unroll
            for (int off = 32; off > 0; off >>= 1) {
                a2 += __shfl_down(a2, off, 64);
                a1 += __shfl_down(a1, off, 64);
                a0 += __shfl_down(a0, off, 64);
            }
            if (tid == 0) {
                u[j] = a0 * third;
                u[16 + j] = a1 * third;
                u[32 + j] = a2 * third;
            }
        }
        float b0 = b2[tid], b1v = b2[64 + tid], b2v = b2[128 + tid];
        float c0 = b0 * tk0 + b1v * tk1 + b2v * tk2;
        float c1 = (b0 + b1v + b2v) * wgv;
#pragma unroll
        for (int off = 32; off > 0; off >>= 1) {
            c0 += __shfl_down(c0, off, 64);
            c1 += __shfl_down(c1, off, 64);
        }
        if (tid == 0) {
            u[48] = c0 * third;
            u[49] = c1 * third;
        }
    }
}

extern "C" void kernel_launch(void* const* d_in, const int* in_sizes, int n_in,
                              void* d_out, int out_size, void* d_ws, size_t ws_size,
                              hipStream_t stream) {
    const float* x   = (const float*)d_in[0];
    const int*   ei  = (const int*)d_in[1];
    const int*   batch = (const int*)d_in[2];
    const float* w1i = (const float*)d_in[3];
    const float* w1w = (const float*)d_in[4];
    const float* w1r = (const float*)d_in[5];
    const float* w1b = (const float*)d_in[6];
    const float* w2i = (const float*)d_in[7];
    const float* w2w = (const float*)d_in[8];
    const float* w2r = (const float*)d_in[9];
    const float* w2b = (const float*)d_in[10];
    const float* wg  = (const float*)d_in[11];
    const float* bg  = (const float*)d_in[12];
    float* out = (float*)d_out;

    // workspace layout (all 16B-aligned)
    uint4* A16   = (uint4*)d_ws;                          // [(N+1)*6] uint4 = bf16[N+1][48]
    uint4* B16   = A16 + (size_t)(NN + 1) * 6;            // same
    float* R     = (float*)(B16 + (size_t)(NN + 1) * 6);  // fp32 [N][48]
    uint4* h1p16 = (uint4*)(R + (size_t)NN * 48);         // [(N+1)*2] uint4 = bf16[N+1][16]
    uint4* g1p16 = h1p16 + (size_t)(NN + 1) * 2;          // same
    float* dinv  = (float*)(g1p16 + (size_t)(NN + 1) * 2);// [N+1] pad to 100004
    float* sv    = dinv + 100004;                         // [N]
    float* z0    = sv + NN;                               // [N]
    float* z1    = z0 + NN;                               // [N]
    float* u     = z1 + NN;                               // [64]
    int*   rowptrp = (int*)(u + 64);                      // [N] packed
    int*   gcur  = rowptrp + NN;                          // [512]
    int*   pairs = gcur + 512;                            // [(NBK+1)*CAPQ]
    int*   esrc  = pairs + (size_t)(NBK + 1) * CAPQ;      // [NBK*CAPE]

    const int T = 256;

    // ---- CSR build (histogram-free, bucketed) ----
    k_init<<<3, T, 0, stream>>>(gcur, A16, B16, h1p16, g1p16, dinv);
    k_part<<<512, T, 0, stream>>>((const int4*)ei, (const int4*)(ei + NE),
                                  gcur, pairs, NE / 4);
    k_bucket<<<NBK, T, 0, stream>>>(pairs, gcur, esrc, rowptrp, dinv, NN);

    // ---- precombined layer-2+head weights + out init ----
    k_comb<<<9, T, 0, stream>>>(w2i, w2w, w2r, w2b, wg, bg, u, out);

    // ---- layer 1 input transforms ----
    k_mmAR<<<2048, T, 0, stream>>>(x, w1i, w1r, w1b, dinv, (ushort4*)A16, (float4*)R, NN);

    // t=0: B16 = bf16( dinv * relu(prop(A16) + R) * dinv ); also sv
    k_prop48<1, 1, 1><<<cdiv((long long)NN * 6, T), T, 0, stream>>>(
        A16, (const float4*)R, rowptrp, esrc, dinv, sv, B16, NN);
    // t=1 agg: A16 = bf16( dinv * prop(B16) )
    k_prop48<0, 0, 0><<<cdiv((long long)NN * 6, T), T, 0, stream>>>(
        B16, nullptr, rowptrp, esrc, dinv, nullptr, A16, NN);
    // h1p16 = bf16(dinv * mean_k relu(A@w1w + R)); z0 = h1.u0
    k_post1<<<cdiv((long long)NN * 4, T), T, 0, stream>>>(
        A16, (const float4*)R, w1w, dinv, u, (ushort4*)h1p16, z0, NN);

    // ---- layer 2 (linearized): g1p16 + z1, then fused g2+score+pool ----
    k_prop16z<<<cdiv((long long)NN * 2, T), T, 0, stream>>>(
        h1p16, rowptrp, esrc, dinv, u, g1p16, z1, NN);
    k_score<<<cdiv((long long)NN * 2, T), T, 0, stream>>>(
        g1p16, rowptrp, esrc, dinv, u, z0, z1, sv, batch, out, NN);
}